// Round 6
// baseline (59027.301 us; speedup 1.0000x reference)
//
#include <hip/hip_runtime.h>
#include <math.h>

#define BB 8
#define NN 2048
#define DD 128
#define HH 128

typedef float f4 __attribute__((ext_vector_type(4)));
typedef float f2 __attribute__((ext_vector_type(2)));

// ---------- fast math helpers ----------
__device__ __forceinline__ float fast_rcp(float x) { return __builtin_amdgcn_rcpf(x); }
__device__ __forceinline__ float clampf(float x, float l) { return fminf(fmaxf(x, -l), l); }
__device__ __forceinline__ float sigm_(float x) {  // x pre-clamped
    return fast_rcp(1.f + __expf(-x));
}
__device__ __forceinline__ float dpp_xor1(float v) {
    return __int_as_float(__builtin_amdgcn_update_dpp(0, __float_as_int(v), 0xB1, 0xF, 0xF, true));
}
__device__ __forceinline__ float dpp_xor2(float v) {
    return __int_as_float(__builtin_amdgcn_update_dpp(0, __float_as_int(v), 0x4E, 0xF, 0xF, true));
}
__device__ __forceinline__ float swz_xor4(float v) {
    return __int_as_float(__builtin_amdgcn_ds_swizzle(__float_as_int(v), 0x101F));
}

// ---------------- Kernel 1: graph aggregation ----------------
#define TI 32
#define TJ 64

__global__ __launch_bounds__(256) void k_agg(const float* __restrict__ x,
                                             const int* __restrict__ adj,
                                             float* __restrict__ xa) {
    __shared__ __align__(16) float xs[TJ][132];
    __shared__ __align__(16) float as[TI][68];
    const int b = blockIdx.y;
    const int i0 = blockIdx.x * TI;
    const int tid = threadIdx.x;
    const int ig = tid >> 5;
    const int dg = tid & 31;
    const float* xb = x + (size_t)b * NN * DD;
    const int* ab = adj + (size_t)b * NN * NN;

    float acc[4][4];
    float deg[4];
#pragma unroll
    for (int i = 0; i < 4; ++i) {
        deg[i] = 0.f;
#pragma unroll
        for (int d = 0; d < 4; ++d) acc[i][d] = 0.f;
    }

    for (int j0 = 0; j0 < NN; j0 += TJ) {
#pragma unroll
        for (int k = 0; k < 8; ++k) {
            int idx = tid + k * 256;
            int row = idx >> 5, c4 = idx & 31;
            float4 v = *(const float4*)(xb + (size_t)(j0 + row) * DD + c4 * 4);
            *(float4*)(&xs[row][c4 * 4]) = v;
        }
#pragma unroll
        for (int k = 0; k < 2; ++k) {
            int idx = tid + k * 256;
            int row = idx >> 4, c4 = idx & 15;
            int4 v = *(const int4*)(ab + (size_t)(i0 + row) * NN + j0 + c4 * 4);
            float4 f;
            f.x = v.x > 0 ? 1.f : 0.f;
            f.y = v.y > 0 ? 1.f : 0.f;
            f.z = v.z > 0 ? 1.f : 0.f;
            f.w = v.w > 0 ? 1.f : 0.f;
            *(float4*)(&as[row][c4 * 4]) = f;
        }
        __syncthreads();
#pragma unroll 4
        for (int jq = 0; jq < TJ; jq += 4) {
            float4 av[4], xv[4];
#pragma unroll
            for (int i = 0; i < 4; ++i) av[i] = *(const float4*)(&as[ig * 4 + i][jq]);
#pragma unroll
            for (int jj = 0; jj < 4; ++jj) xv[jj] = *(const float4*)(&xs[jq + jj][dg * 4]);
#pragma unroll
            for (int i = 0; i < 4; ++i) {
                const float* ap = (const float*)&av[i];
#pragma unroll
                for (int jj = 0; jj < 4; ++jj) {
                    float a = ap[jj];
                    const float* xp4 = (const float*)&xv[jj];
                    deg[i] += a;
                    acc[i][0] = fmaf(a, xp4[0], acc[i][0]);
                    acc[i][1] = fmaf(a, xp4[1], acc[i][1]);
                    acc[i][2] = fmaf(a, xp4[2], acc[i][2]);
                    acc[i][3] = fmaf(a, xp4[3], acc[i][3]);
                }
            }
        }
        __syncthreads();
    }
#pragma unroll
    for (int i = 0; i < 4; ++i) {
        int gi = i0 + ig * 4 + i;
        float r = fast_rcp(1.f + deg[i]);
        float4 xv = *(const float4*)(xb + (size_t)gi * DD + dg * 4);
        float4 o;
        o.x = (xv.x + acc[i][0]) * r;
        o.y = (xv.y + acc[i][1]) * r;
        o.z = (xv.z + acc[i][2]) * r;
        o.w = (xv.w + acc[i][3]) * r;
        *(float4*)(xa + ((size_t)b * NN + gi) * DD + dg * 4) = o;
    }
}

// ---------------- Kernel 2: input projection (both dirs) ----------------
// Writes xp pre-permuted for k_lstm: gate (unit u, type j) -> slot 4*u+j.
// Backward dir also pre-reversed in time.
#define MT 64
#define GT 32

__global__ __launch_bounds__(256) void k_proj(const float* __restrict__ xa,
                                              const float* __restrict__ wif,
                                              const float* __restrict__ wib,
                                              const float* __restrict__ bif,
                                              const float* __restrict__ bhf,
                                              const float* __restrict__ bib,
                                              const float* __restrict__ bhb,
                                              float* __restrict__ xpf,
                                              float* __restrict__ xpb) {
    __shared__ __align__(16) float xs[MT][132];
    __shared__ __align__(16) float wl[GT][132];
    const int r0 = blockIdx.x * MT;
    const int g0 = blockIdx.y * GT;
    const int tid = threadIdx.x;
#pragma unroll
    for (int k = 0; k < 8; ++k) {
        int idx = tid + k * 256;
        int row = idx >> 5, c4 = idx & 31;
        int r = r0 + row;
        int t = r >> 3, bb = r & 7;
        float4 v = *(const float4*)(xa + ((size_t)bb * NN + t) * DD + c4 * 4);
        *(float4*)(&xs[row][c4 * 4]) = v;
    }
#pragma unroll
    for (int k = 0; k < 4; ++k) {
        int idx = tid + k * 256;
        int row = idx >> 5, c4 = idx & 31;
        int g = g0 + row;
        const float* wsrc = (g < 512) ? (wif + (size_t)g * DD) : (wib + (size_t)(g - 512) * DD);
        *(float4*)(&wl[row][c4 * 4]) = *(const float4*)(wsrc + c4 * 4);
    }
    __syncthreads();
    const int mg = tid >> 4;
    const int gg = tid & 15;
    float acc[4][2];
#pragma unroll
    for (int i = 0; i < 4; ++i) { acc[i][0] = 0.f; acc[i][1] = 0.f; }
#pragma unroll 8
    for (int d4 = 0; d4 < 32; ++d4) {
        float4 xv[4], wv[2];
#pragma unroll
        for (int i = 0; i < 4; ++i) xv[i] = *(const float4*)(&xs[mg * 4 + i][d4 * 4]);
        wv[0] = *(const float4*)(&wl[gg * 2 + 0][d4 * 4]);
        wv[1] = *(const float4*)(&wl[gg * 2 + 1][d4 * 4]);
#pragma unroll
        for (int i = 0; i < 4; ++i) {
#pragma unroll
            for (int j = 0; j < 2; ++j) {
                acc[i][j] = fmaf(xv[i].x, wv[j].x, acc[i][j]);
                acc[i][j] = fmaf(xv[i].y, wv[j].y, acc[i][j]);
                acc[i][j] = fmaf(xv[i].z, wv[j].z, acc[i][j]);
                acc[i][j] = fmaf(xv[i].w, wv[j].w, acc[i][j]);
            }
        }
    }
#pragma unroll
    for (int j = 0; j < 2; ++j) {
        int g = g0 + gg * 2 + j;
        float bias = (g < 512) ? (bif[g] + bhf[g]) : (bib[g - 512] + bhb[g - 512]);
#pragma unroll
        for (int i = 0; i < 4; ++i) {
            int r = r0 + mg * 4 + i;
            int t = r >> 3, bb = r & 7;
            float v = acc[i][j] + bias;
            if (g < 512) {
                int p = 4 * (g & 127) + (g >> 7);
                xpf[((size_t)t * BB + bb) * 512 + p] = v;
            } else {
                int gb = g - 512;
                int p = 4 * (gb & 127) + (gb >> 7);
                xpb[((size_t)(NN - 1 - t) * BB + bb) * 512 + p] = v;
            }
        }
    }
}

// ---------------- Kernel 3: LSTM recurrence ----------------
// 1024 threads/block, one block per (batch,dir) -> 1 block/CU, 4 waves/SIMD
// (VGPR budget 128). Thread (u, jp, s): u=tid>>3 unit, jp=(tid>>2)&1 gate-pair
// ({i,f} or {g,o}), s=tid&3 h-slice of 32 cols. W per thread = 2x32 = 64 VGPRs.
// Reduce over s via 2 quad-DPP xor-adds; cross-gate via 2 ds_swizzle(xor4);
// every lane redundantly computes c,h (uniform scaled-sigmoid activations,
// tanh(x)=2*sigm(2x)-1) -> no divergence, no gate-exchange LDS, 1 barrier/step.
__global__ __attribute__((amdgpu_flat_work_group_size(1024, 1024), amdgpu_waves_per_eu(4, 4)))
void k_lstm(const float* __restrict__ xpf,
            const float* __restrict__ xpb,
            const float* __restrict__ whf,
            const float* __restrict__ whb,
            float* __restrict__ out) {
    const int b = blockIdx.x;
    const int dir = blockIdx.y;
    const float* __restrict__ xp = (dir ? xpb : xpf) + (size_t)b * 512;
    const float* __restrict__ wh = dir ? whb : whf;
    const int tid = threadIdx.x;  // 0..1023
    const int u = tid >> 3;       // unit 0..127
    const int jp = (tid >> 2) & 1;  // 0:{i,f} 1:{g,o}
    const int s = tid & 3;        // h-col slice [32s, 32s+32)

    __shared__ __align__(16) float h_lds[2][HH];

    // W rows (2jp)*128+u and (2jp+1)*128+u, cols [32s, 32s+32) as 8 f4 each.
    f4 wA[8], wB[8];
    const float* rowA = wh + (size_t)(2 * jp * HH + u) * HH + s * 32;
    const float* rowB = wh + (size_t)((2 * jp + 1) * HH + u) * HH + s * 32;
#pragma unroll
    for (int k = 0; k < 8; ++k) {
        wA[k] = *(const f4*)(rowA + k * 4);
        wB[k] = *(const f4*)(rowB + k * 4);
    }

    // activation constants: a1 = A1*sigm(m1*clamp(p1,CL1)) + B1
    // jp=0: a1=sigm(i);     jp=1: a1=tanh(g)=2*sigm(2g)-1
    const float m1 = jp ? 2.f : 1.f;
    const float A1 = jp ? 2.f : 1.f;
    const float B1 = jp ? -1.f : 0.f;
    const float CL1 = jp ? 15.f : 30.f;
    const float sel = (s == 0) ? 1.f : 0.f;  // xp injected once per gate

    if (tid < HH) h_lds[0][tid] = 0.f;
    __syncthreads();

    float c = 0.f, h = 0.f;
    f2 xpv = *(const f2*)(xp + 4 * u + 2 * jp);  // step 0
    int cur = 0;

    for (int step = 0; step < NN; ++step) {
        int sn = step + 1 < NN ? step + 1 : NN - 1;
        f2 xpn = *(const f2*)(xp + (size_t)sn * BB * 512 + 4 * u + 2 * jp);

        // keep W arch-VGPR-resident (no-op when already there)
        asm volatile("" : "+v"(wA[0]), "+v"(wA[1]), "+v"(wA[2]), "+v"(wA[3]), "+v"(wA[4]),
                       "+v"(wA[5]), "+v"(wA[6]), "+v"(wA[7]), "+v"(wB[0]), "+v"(wB[1]),
                       "+v"(wB[2]), "+v"(wB[3]), "+v"(wB[4]), "+v"(wB[5]), "+v"(wB[6]),
                       "+v"(wB[7]));

        f2 aA0 = {0.f, 0.f}, aA1 = aA0, aB0 = aA0, aB1 = aA0;
#pragma unroll
        for (int m = 0; m < 8; ++m) {
            int k = (m + 2 * s) & 7;  // bank-rotated read order across slices
            f4 hv = *(const f4*)(&h_lds[cur][s * 32 + k * 4]);
            f2 hlo = {hv.x, hv.y}, hhi = {hv.z, hv.w};
            f2 alo = {wA[k].x, wA[k].y}, ahi = {wA[k].z, wA[k].w};
            f2 blo = {wB[k].x, wB[k].y}, bhi = {wB[k].z, wB[k].w};
            aA0 = __builtin_elementwise_fma(alo, hlo, aA0);
            aA1 = __builtin_elementwise_fma(ahi, hhi, aA1);
            aB0 = __builtin_elementwise_fma(blo, hlo, aB0);
            aB1 = __builtin_elementwise_fma(bhi, hhi, aB1);
        }
        f2 accA = aA0 + aA1;
        f2 accB = aB0 + aB1;
        float p1 = accA.x + accA.y;
        float p2 = accB.x + accB.y;
        p1 = fmaf(sel, xpv.x, p1);
        p2 = fmaf(sel, xpv.y, p2);
        // reduce over the 4 slices (lane bits 0,1) - butterfly, identical in all lanes
        p1 += dpp_xor1(p1);
        p1 += dpp_xor2(p1);
        p2 += dpp_xor1(p2);
        p2 += dpp_xor2(p2);
        // activations (uniform code path)
        float a1 = fmaf(A1, sigm_(m1 * clampf(p1, CL1)), B1);  // jp0: sig(i), jp1: tanh(g)
        float a2 = sigm_(clampf(p2, 30.f));                    // jp0: sig(f), jp1: sig(o)
        // cross gate-pair exchange (lane bit 2)
        float sw1 = swz_xor4(a1);  // jp0 gets tanh(g), jp1 gets sig(i)
        float sw2 = swz_xor4(a2);  // jp0 gets sig(o),  jp1 gets sig(f)
        float sf = jp ? sw2 : a2;
        float so = jp ? a2 : sw2;
        c = fmaf(sf, c, a1 * sw1);  // sig(f)*c + sig(i)*tanh(g), all lanes identical
        float th = fmaf(2.f, sigm_(2.f * clampf(c, 15.f)), -1.f);  // tanh(c)
        h = th * so;
        if ((tid & 7) == 0) h_lds[cur ^ 1][u] = h;
        __syncthreads();
        cur ^= 1;
        xpv = xpn;
    }
    if ((tid & 7) == 0) out[(size_t)b * 256 + dir * HH + u] = h;
}

extern "C" void kernel_launch(void* const* d_in, const int* in_sizes, int n_in,
                              void* d_out, int out_size, void* d_ws, size_t ws_size,
                              hipStream_t stream) {
    const float* x = (const float*)d_in[0];
    const int* adj = (const int*)d_in[1];
    const float* wif = (const float*)d_in[2];
    const float* whf = (const float*)d_in[3];
    const float* bif = (const float*)d_in[4];
    const float* bhf = (const float*)d_in[5];
    const float* wib = (const float*)d_in[6];
    const float* whb = (const float*)d_in[7];
    const float* bib = (const float*)d_in[8];
    const float* bhb = (const float*)d_in[9];
    float* out = (float*)d_out;

    float* xa = (float*)d_ws;                            // [B][N][D]
    float* xpf = xa + (size_t)BB * NN * DD;              // [N][B][512]
    float* xpb = xpf + (size_t)NN * BB * 512;            // [N][B][512]

    k_agg<<<dim3(NN / TI, BB), 256, 0, stream>>>(x, adj, xa);
    k_proj<<<dim3((NN * BB) / MT, 1024 / GT), 256, 0, stream>>>(xa, wif, wib, bif, bhf, bib, bhb,
                                                                xpf, xpb);
    k_lstm<<<dim3(BB, 2), 1024, 0, stream>>>(xpf, xpb, whf, whb, out);
}

// Round 8
// 58893.414 us; speedup vs baseline: 1.0023x; 1.0023x over previous
//
#include <hip/hip_runtime.h>
#include <math.h>

#define BB 8
#define NN 2048
#define DD 128
#define HH 128

typedef float f4 __attribute__((ext_vector_type(4)));
typedef float f2 __attribute__((ext_vector_type(2)));

// ---------- fast math helpers ----------
__device__ __forceinline__ float fast_rcp(float x) { return __builtin_amdgcn_rcpf(x); }
__device__ __forceinline__ float clampf(float x, float l) { return fminf(fmaxf(x, -l), l); }
__device__ __forceinline__ float sigm_(float x) {  // x pre-clamped
    return fast_rcp(1.f + __expf(-x));
}
__device__ __forceinline__ float dpp_xor1(float v) {
    return __int_as_float(__builtin_amdgcn_update_dpp(0, __float_as_int(v), 0xB1, 0xF, 0xF, true));
}
__device__ __forceinline__ float dpp_xor2(float v) {
    return __int_as_float(__builtin_amdgcn_update_dpp(0, __float_as_int(v), 0x4E, 0xF, 0xF, true));
}
__device__ __forceinline__ float swz_xor4(float v) {
    return __int_as_float(__builtin_amdgcn_ds_swizzle(__float_as_int(v), 0x101F));
}

// ---------------- Kernel 1: graph aggregation ----------------
#define TI 32
#define TJ 64

__global__ __launch_bounds__(256) void k_agg(const float* __restrict__ x,
                                             const int* __restrict__ adj,
                                             float* __restrict__ xa) {
    __shared__ __align__(16) float xs[TJ][132];
    __shared__ __align__(16) float as[TI][68];
    const int b = blockIdx.y;
    const int i0 = blockIdx.x * TI;
    const int tid = threadIdx.x;
    const int ig = tid >> 5;
    const int dg = tid & 31;
    const float* xb = x + (size_t)b * NN * DD;
    const int* ab = adj + (size_t)b * NN * NN;

    float acc[4][4];
    float deg[4];
#pragma unroll
    for (int i = 0; i < 4; ++i) {
        deg[i] = 0.f;
#pragma unroll
        for (int d = 0; d < 4; ++d) acc[i][d] = 0.f;
    }

    for (int j0 = 0; j0 < NN; j0 += TJ) {
#pragma unroll
        for (int k = 0; k < 8; ++k) {
            int idx = tid + k * 256;
            int row = idx >> 5, c4 = idx & 31;
            float4 v = *(const float4*)(xb + (size_t)(j0 + row) * DD + c4 * 4);
            *(float4*)(&xs[row][c4 * 4]) = v;
        }
#pragma unroll
        for (int k = 0; k < 2; ++k) {
            int idx = tid + k * 256;
            int row = idx >> 4, c4 = idx & 15;
            int4 v = *(const int4*)(ab + (size_t)(i0 + row) * NN + j0 + c4 * 4);
            float4 f;
            f.x = v.x > 0 ? 1.f : 0.f;
            f.y = v.y > 0 ? 1.f : 0.f;
            f.z = v.z > 0 ? 1.f : 0.f;
            f.w = v.w > 0 ? 1.f : 0.f;
            *(float4*)(&as[row][c4 * 4]) = f;
        }
        __syncthreads();
#pragma unroll 4
        for (int jq = 0; jq < TJ; jq += 4) {
            float4 av[4], xv[4];
#pragma unroll
            for (int i = 0; i < 4; ++i) av[i] = *(const float4*)(&as[ig * 4 + i][jq]);
#pragma unroll
            for (int jj = 0; jj < 4; ++jj) xv[jj] = *(const float4*)(&xs[jq + jj][dg * 4]);
#pragma unroll
            for (int i = 0; i < 4; ++i) {
                const float* ap = (const float*)&av[i];
#pragma unroll
                for (int jj = 0; jj < 4; ++jj) {
                    float a = ap[jj];
                    const float* xp4 = (const float*)&xv[jj];
                    deg[i] += a;
                    acc[i][0] = fmaf(a, xp4[0], acc[i][0]);
                    acc[i][1] = fmaf(a, xp4[1], acc[i][1]);
                    acc[i][2] = fmaf(a, xp4[2], acc[i][2]);
                    acc[i][3] = fmaf(a, xp4[3], acc[i][3]);
                }
            }
        }
        __syncthreads();
    }
#pragma unroll
    for (int i = 0; i < 4; ++i) {
        int gi = i0 + ig * 4 + i;
        float r = fast_rcp(1.f + deg[i]);
        float4 xv = *(const float4*)(xb + (size_t)gi * DD + dg * 4);
        float4 o;
        o.x = (xv.x + acc[i][0]) * r;
        o.y = (xv.y + acc[i][1]) * r;
        o.z = (xv.z + acc[i][2]) * r;
        o.w = (xv.w + acc[i][3]) * r;
        *(float4*)(xa + ((size_t)b * NN + gi) * DD + dg * 4) = o;
    }
}

// ---------------- Kernel 2: input projection (both dirs) ----------------
// Writes xp pre-permuted for k_lstm: gate (unit u, type j) -> slot 4*u+j.
// Backward dir also pre-reversed in time.
#define MT 64
#define GT 32

__global__ __launch_bounds__(256) void k_proj(const float* __restrict__ xa,
                                              const float* __restrict__ wif,
                                              const float* __restrict__ wib,
                                              const float* __restrict__ bif,
                                              const float* __restrict__ bhf,
                                              const float* __restrict__ bib,
                                              const float* __restrict__ bhb,
                                              float* __restrict__ xpf,
                                              float* __restrict__ xpb) {
    __shared__ __align__(16) float xs[MT][132];
    __shared__ __align__(16) float wl[GT][132];
    const int r0 = blockIdx.x * MT;
    const int g0 = blockIdx.y * GT;
    const int tid = threadIdx.x;
#pragma unroll
    for (int k = 0; k < 8; ++k) {
        int idx = tid + k * 256;
        int row = idx >> 5, c4 = idx & 31;
        int r = r0 + row;
        int t = r >> 3, bb = r & 7;
        float4 v = *(const float4*)(xa + ((size_t)bb * NN + t) * DD + c4 * 4);
        *(float4*)(&xs[row][c4 * 4]) = v;
    }
#pragma unroll
    for (int k = 0; k < 4; ++k) {
        int idx = tid + k * 256;
        int row = idx >> 5, c4 = idx & 31;
        int g = g0 + row;
        const float* wsrc = (g < 512) ? (wif + (size_t)g * DD) : (wib + (size_t)(g - 512) * DD);
        *(float4*)(&wl[row][c4 * 4]) = *(const float4*)(wsrc + c4 * 4);
    }
    __syncthreads();
    const int mg = tid >> 4;
    const int gg = tid & 15;
    float acc[4][2];
#pragma unroll
    for (int i = 0; i < 4; ++i) { acc[i][0] = 0.f; acc[i][1] = 0.f; }
#pragma unroll 8
    for (int d4 = 0; d4 < 32; ++d4) {
        float4 xv[4], wv[2];
#pragma unroll
        for (int i = 0; i < 4; ++i) xv[i] = *(const float4*)(&xs[mg * 4 + i][d4 * 4]);
        wv[0] = *(const float4*)(&wl[gg * 2 + 0][d4 * 4]);
        wv[1] = *(const float4*)(&wl[gg * 2 + 1][d4 * 4]);
#pragma unroll
        for (int i = 0; i < 4; ++i) {
#pragma unroll
            for (int j = 0; j < 2; ++j) {
                acc[i][j] = fmaf(xv[i].x, wv[j].x, acc[i][j]);
                acc[i][j] = fmaf(xv[i].y, wv[j].y, acc[i][j]);
                acc[i][j] = fmaf(xv[i].z, wv[j].z, acc[i][j]);
                acc[i][j] = fmaf(xv[i].w, wv[j].w, acc[i][j]);
            }
        }
    }
#pragma unroll
    for (int j = 0; j < 2; ++j) {
        int g = g0 + gg * 2 + j;
        float bias = (g < 512) ? (bif[g] + bhf[g]) : (bib[g - 512] + bhb[g - 512]);
#pragma unroll
        for (int i = 0; i < 4; ++i) {
            int r = r0 + mg * 4 + i;
            int t = r >> 3, bb = r & 7;
            float v = acc[i][j] + bias;
            if (g < 512) {
                int p = 4 * (g & 127) + (g >> 7);
                xpf[((size_t)t * BB + bb) * 512 + p] = v;
            } else {
                int gb = g - 512;
                int p = 4 * (gb & 127) + (gb >> 7);
                xpb[((size_t)(NN - 1 - t) * BB + bb) * 512 + p] = v;
            }
        }
    }
}

// ---------------- Kernel 3: LSTM recurrence (fp32, R6 layout) ----------------
// 1024 threads/block, one block per (batch,dir). Thread (u, jp, s):
// u=tid>>3 unit, jp=(tid>>2)&1 gate-pair ({i,f}/{g,o}), s=tid&3 h-slice.
// W per thread = 2x32 fp32 = 64 VGPRs. Reduce over s via 2 quad-DPP xor-adds;
// cross-gate via ds_swizzle(xor4); redundant update; 1 barrier/step.
// R6 failed because the RA budgeted 64 VGPRs (8 waves/EU) and scratch-spilled
// W (WRITE_SIZE 3.4MB). Fix: ~101KB LDS pad physically limits residency to
// 1 block/CU -> achievable occupancy 4 waves/SIMD -> VGPR budget 128, which
// the RA's occupancy calc must respect regardless of attribute parsing.
__global__ __launch_bounds__(1024, 4)
void k_lstm(const float* __restrict__ xpf,
            const float* __restrict__ xpb,
            const float* __restrict__ whf,
            const float* __restrict__ whb,
            float* __restrict__ out) {
    const int b = blockIdx.x;
    const int dir = blockIdx.y;
    const float* __restrict__ xp = (dir ? xpb : xpf) + (size_t)b * 512;
    const float* __restrict__ wh = dir ? whb : whf;
    const int tid = threadIdx.x;    // 0..1023
    const int u = tid >> 3;         // unit 0..127
    const int jp = (tid >> 2) & 1;  // 0:{i,f} 1:{g,o}
    const int s = tid & 3;          // h-col slice [32s, 32s+32)

    __shared__ __align__(16) float h_lds[2][HH];
    __shared__ float lds_pad[25600];  // 100KB: forces 1 block/CU (occupancy 4 waves/SIMD)

    // W rows (2jp)*128+u and (2jp+1)*128+u, cols [32s, 32s+32) as 8 f4 each.
    f4 wA[8], wB[8];
    const float* rowA = wh + (size_t)(2 * jp * HH + u) * HH + s * 32;
    const float* rowB = wh + (size_t)((2 * jp + 1) * HH + u) * HH + s * 32;
#pragma unroll
    for (int k = 0; k < 8; ++k) {
        wA[k] = *(const f4*)(rowA + k * 4);
        wB[k] = *(const f4*)(rowB + k * 4);
    }

    // activation constants: a1 = A1*sigm(m1*clamp(p1,CL1)) + B1
    // jp=0: a1=sigm(i);     jp=1: a1=tanh(g)=2*sigm(2g)-1
    const float m1 = jp ? 2.f : 1.f;
    const float A1 = jp ? 2.f : 1.f;
    const float B1 = jp ? -1.f : 0.f;
    const float CL1 = jp ? 15.f : 30.f;
    const float sel = (s == 0) ? 1.f : 0.f;  // xp injected once per gate

    if (tid < HH) h_lds[0][tid] = 0.f;
    if (tid == 0) {
        volatile float* pv = lds_pad;  // volatile: allocation can't be DCE'd
        pv[0] = 0.f;
    }
    __syncthreads();

    float c = 0.f, h = 0.f;
    f2 xpv = *(const f2*)(xp + 4 * u + 2 * jp);  // step 0
    int cur = 0;

    for (int step = 0; step < NN; ++step) {
        int sn = step + 1 < NN ? step + 1 : NN - 1;
        f2 xpn = *(const f2*)(xp + (size_t)sn * BB * 512 + 4 * u + 2 * jp);

        // keep W arch-VGPR-resident (no-op when already there)
        asm volatile("" : "+v"(wA[0]), "+v"(wA[1]), "+v"(wA[2]), "+v"(wA[3]), "+v"(wA[4]),
                       "+v"(wA[5]), "+v"(wA[6]), "+v"(wA[7]), "+v"(wB[0]), "+v"(wB[1]),
                       "+v"(wB[2]), "+v"(wB[3]), "+v"(wB[4]), "+v"(wB[5]), "+v"(wB[6]),
                       "+v"(wB[7]));

        f2 aA0 = {0.f, 0.f}, aA1 = aA0, aB0 = aA0, aB1 = aA0;
#pragma unroll
        for (int m = 0; m < 8; ++m) {
            int k = (m + 2 * s) & 7;  // bank-rotated read order across slices
            f4 hv = *(const f4*)(&h_lds[cur][s * 32 + k * 4]);
            f2 hlo = {hv.x, hv.y}, hhi = {hv.z, hv.w};
            f2 alo = {wA[k].x, wA[k].y}, ahi = {wA[k].z, wA[k].w};
            f2 blo = {wB[k].x, wB[k].y}, bhi = {wB[k].z, wB[k].w};
            aA0 = __builtin_elementwise_fma(alo, hlo, aA0);
            aA1 = __builtin_elementwise_fma(ahi, hhi, aA1);
            aB0 = __builtin_elementwise_fma(blo, hlo, aB0);
            aB1 = __builtin_elementwise_fma(bhi, hhi, aB1);
        }
        f2 accA = aA0 + aA1;
        f2 accB = aB0 + aB1;
        float p1 = accA.x + accA.y;
        float p2 = accB.x + accB.y;
        p1 = fmaf(sel, xpv.x, p1);
        p2 = fmaf(sel, xpv.y, p2);
        // reduce over the 4 slices (lane bits 0,1) - butterfly, identical in all lanes
        p1 += dpp_xor1(p1);
        p1 += dpp_xor2(p1);
        p2 += dpp_xor1(p2);
        p2 += dpp_xor2(p2);
        // activations (uniform code path)
        float a1 = fmaf(A1, sigm_(m1 * clampf(p1, CL1)), B1);  // jp0: sig(i), jp1: tanh(g)
        float a2 = sigm_(clampf(p2, 30.f));                    // jp0: sig(f), jp1: sig(o)
        // cross gate-pair exchange (lane bit 2)
        float sw1 = swz_xor4(a1);  // jp0 gets tanh(g), jp1 gets sig(i)
        float sw2 = swz_xor4(a2);  // jp0 gets sig(o),  jp1 gets sig(f)
        float sf = jp ? sw2 : a2;
        float so = jp ? a2 : sw2;
        c = fmaf(sf, c, a1 * sw1);  // sig(f)*c + sig(i)*tanh(g), all lanes identical
        float th = fmaf(2.f, sigm_(2.f * clampf(c, 15.f)), -1.f);  // tanh(c)
        h = th * so;
        if ((tid & 7) == 0) h_lds[cur ^ 1][u] = h;
        __syncthreads();
        cur ^= 1;
        xpv = xpn;
    }
    if ((tid & 7) == 0) out[(size_t)b * 256 + dir * HH + u] = h;
}

extern "C" void kernel_launch(void* const* d_in, const int* in_sizes, int n_in,
                              void* d_out, int out_size, void* d_ws, size_t ws_size,
                              hipStream_t stream) {
    const float* x = (const float*)d_in[0];
    const int* adj = (const int*)d_in[1];
    const float* wif = (const float*)d_in[2];
    const float* whf = (const float*)d_in[3];
    const float* bif = (const float*)d_in[4];
    const float* bhf = (const float*)d_in[5];
    const float* wib = (const float*)d_in[6];
    const float* whb = (const float*)d_in[7];
    const float* bib = (const float*)d_in[8];
    const float* bhb = (const float*)d_in[9];
    float* out = (float*)d_out;

    float* xa = (float*)d_ws;                            // [B][N][D]
    float* xpf = xa + (size_t)BB * NN * DD;              // [N][B][512]
    float* xpb = xpf + (size_t)NN * BB * 512;            // [N][B][512]

    k_agg<<<dim3(NN / TI, BB), 256, 0, stream>>>(x, adj, xa);
    k_proj<<<dim3((NN * BB) / MT, 1024 / GT), 256, 0, stream>>>(xa, wif, wib, bif, bhf, bib, bhb,
                                                                xpf, xpb);
    k_lstm<<<dim3(BB, 2), 1024, 0, stream>>>(xpf, xpb, whf, whb, out);
}

// Round 10
// 1711.302 us; speedup vs baseline: 34.4926x; 34.4144x over previous
//
#include <hip/hip_runtime.h>
#include <math.h>

#define BB 8
#define NN 2048
#define DD 128
#define HH 128

typedef float f4 __attribute__((ext_vector_type(4)));

__device__ __forceinline__ float fast_rcp(float x) { return __builtin_amdgcn_rcpf(x); }

// ---------------- Kernel 1: graph aggregation ----------------
#define TI 32
#define TJ 64

__global__ __launch_bounds__(256) void k_agg(const float* __restrict__ x,
                                             const int* __restrict__ adj,
                                             float* __restrict__ xa) {
    __shared__ __align__(16) float xs[TJ][132];
    __shared__ __align__(16) float as[TI][68];
    const int b = blockIdx.y;
    const int i0 = blockIdx.x * TI;
    const int tid = threadIdx.x;
    const int ig = tid >> 5;
    const int dg = tid & 31;
    const float* xb = x + (size_t)b * NN * DD;
    const int* ab = adj + (size_t)b * NN * NN;

    float acc[4][4];
    float deg[4];
#pragma unroll
    for (int i = 0; i < 4; ++i) {
        deg[i] = 0.f;
#pragma unroll
        for (int d = 0; d < 4; ++d) acc[i][d] = 0.f;
    }

    for (int j0 = 0; j0 < NN; j0 += TJ) {
#pragma unroll
        for (int k = 0; k < 8; ++k) {
            int idx = tid + k * 256;
            int row = idx >> 5, c4 = idx & 31;
            float4 v = *(const float4*)(xb + (size_t)(j0 + row) * DD + c4 * 4);
            *(float4*)(&xs[row][c4 * 4]) = v;
        }
#pragma unroll
        for (int k = 0; k < 2; ++k) {
            int idx = tid + k * 256;
            int row = idx >> 4, c4 = idx & 15;
            int4 v = *(const int4*)(ab + (size_t)(i0 + row) * NN + j0 + c4 * 4);
            float4 f;
            f.x = v.x > 0 ? 1.f : 0.f;
            f.y = v.y > 0 ? 1.f : 0.f;
            f.z = v.z > 0 ? 1.f : 0.f;
            f.w = v.w > 0 ? 1.f : 0.f;
            *(float4*)(&as[row][c4 * 4]) = f;
        }
        __syncthreads();
#pragma unroll 4
        for (int jq = 0; jq < TJ; jq += 4) {
            float4 av[4], xv[4];
#pragma unroll
            for (int i = 0; i < 4; ++i) av[i] = *(const float4*)(&as[ig * 4 + i][jq]);
#pragma unroll
            for (int jj = 0; jj < 4; ++jj) xv[jj] = *(const float4*)(&xs[jq + jj][dg * 4]);
#pragma unroll
            for (int i = 0; i < 4; ++i) {
                const float* ap = (const float*)&av[i];
#pragma unroll
                for (int jj = 0; jj < 4; ++jj) {
                    float a = ap[jj];
                    const float* xp4 = (const float*)&xv[jj];
                    deg[i] += a;
                    acc[i][0] = fmaf(a, xp4[0], acc[i][0]);
                    acc[i][1] = fmaf(a, xp4[1], acc[i][1]);
                    acc[i][2] = fmaf(a, xp4[2], acc[i][2]);
                    acc[i][3] = fmaf(a, xp4[3], acc[i][3]);
                }
            }
        }
        __syncthreads();
    }
#pragma unroll
    for (int i = 0; i < 4; ++i) {
        int gi = i0 + ig * 4 + i;
        float r = fast_rcp(1.f + deg[i]);
        float4 xv = *(const float4*)(xb + (size_t)gi * DD + dg * 4);
        float4 o;
        o.x = (xv.x + acc[i][0]) * r;
        o.y = (xv.y + acc[i][1]) * r;
        o.z = (xv.z + acc[i][2]) * r;
        o.w = (xv.w + acc[i][3]) * r;
        *(float4*)(xa + ((size_t)b * NN + gi) * DD + dg * 4) = o;
    }
}

// ---------------- Kernel 2: input projection (both dirs) ----------------
// Writes xp pre-permuted for k_lstm: gate (unit u, type j) -> slot 4*u+j.
// Backward dir also pre-reversed in time.
#define MT 64
#define GT 32

__global__ __launch_bounds__(256) void k_proj(const float* __restrict__ xa,
                                              const float* __restrict__ wif,
                                              const float* __restrict__ wib,
                                              const float* __restrict__ bif,
                                              const float* __restrict__ bhf,
                                              const float* __restrict__ bib,
                                              const float* __restrict__ bhb,
                                              float* __restrict__ xpf,
                                              float* __restrict__ xpb) {
    __shared__ __align__(16) float xs[MT][132];
    __shared__ __align__(16) float wl[GT][132];
    const int r0 = blockIdx.x * MT;
    const int g0 = blockIdx.y * GT;
    const int tid = threadIdx.x;
#pragma unroll
    for (int k = 0; k < 8; ++k) {
        int idx = tid + k * 256;
        int row = idx >> 5, c4 = idx & 31;
        int r = r0 + row;
        int t = r >> 3, bb = r & 7;
        float4 v = *(const float4*)(xa + ((size_t)bb * NN + t) * DD + c4 * 4);
        *(float4*)(&xs[row][c4 * 4]) = v;
    }
#pragma unroll
    for (int k = 0; k < 4; ++k) {
        int idx = tid + k * 256;
        int row = idx >> 5, c4 = idx & 31;
        int g = g0 + row;
        const float* wsrc = (g < 512) ? (wif + (size_t)g * DD) : (wib + (size_t)(g - 512) * DD);
        *(float4*)(&wl[row][c4 * 4]) = *(const float4*)(wsrc + c4 * 4);
    }
    __syncthreads();
    const int mg = tid >> 4;
    const int gg = tid & 15;
    float acc[4][2];
#pragma unroll
    for (int i = 0; i < 4; ++i) { acc[i][0] = 0.f; acc[i][1] = 0.f; }
#pragma unroll 8
    for (int d4 = 0; d4 < 32; ++d4) {
        float4 xv[4], wv[2];
#pragma unroll
        for (int i = 0; i < 4; ++i) xv[i] = *(const float4*)(&xs[mg * 4 + i][d4 * 4]);
        wv[0] = *(const float4*)(&wl[gg * 2 + 0][d4 * 4]);
        wv[1] = *(const float4*)(&wl[gg * 2 + 1][d4 * 4]);
#pragma unroll
        for (int i = 0; i < 4; ++i) {
#pragma unroll
            for (int j = 0; j < 2; ++j) {
                acc[i][j] = fmaf(xv[i].x, wv[j].x, acc[i][j]);
                acc[i][j] = fmaf(xv[i].y, wv[j].y, acc[i][j]);
                acc[i][j] = fmaf(xv[i].z, wv[j].z, acc[i][j]);
                acc[i][j] = fmaf(xv[i].w, wv[j].w, acc[i][j]);
            }
        }
    }
#pragma unroll
    for (int j = 0; j < 2; ++j) {
        int g = g0 + gg * 2 + j;
        float bias = (g < 512) ? (bif[g] + bhf[g]) : (bib[g - 512] + bhb[g - 512]);
#pragma unroll
        for (int i = 0; i < 4; ++i) {
            int r = r0 + mg * 4 + i;
            int t = r >> 3, bb = r & 7;
            float v = acc[i][j] + bias;
            if (g < 512) {
                int p = 4 * (g & 127) + (g >> 7);
                xpf[((size_t)t * BB + bb) * 512 + p] = v;
            } else {
                int gb = g - 512;
                int p = 4 * (gb & 127) + (gb >> 7);
                xpb[((size_t)(NN - 1 - t) * BB + bb) * 512 + p] = v;
            }
        }
    }
}

// ---------------- Kernel 3: LSTM recurrence (full inline-asm loop) ---------
// One block per (batch,dir), 512 threads. Quad q owns unit q; lane jq covers
// h-cols [32jq,32jq+32) for all 4 gate types. Entire 2048-step loop is one
// asm block with hand-allocated registers:
//   v8-v17 temps/gates/c/h   v18 counter  v19-v23 xp/addrs
//   v24-v31 packed accs      v32-v63 h    v64-v191 W (128 VGPRs, loaded once)
// R9 lesson: CDNA trans ops (v_exp/v_rcp) need >=1 manual wait state before a
// VALU consumer (compiler inserts them for intrinsics; hand asm must too).
// All trans->use gaps here are >=2 instructions (interleaved 4 gate chains,
// s_nop in the lone tanh(c) chain).

#define STRG(x) #x
#define WLD(R0, R3, WOFF, IMM)                                            \
    "global_load_dwordx4 v[" STRG(R0) ":" STRG(R3) "], %[" STRG(WOFF) "], %[whs] offset:" STRG(IMM) "\n\t"
#define PKQ(H0, H1, A0, A1, B0, B1, C0, C1, D0, D1)                                        \
    "v_pk_fma_f32 v[24:25], v[" STRG(A0) ":" STRG(A1) "], v[" STRG(H0) ":" STRG(H1) "], v[24:25]\n\t" \
    "v_pk_fma_f32 v[26:27], v[" STRG(B0) ":" STRG(B1) "], v[" STRG(H0) ":" STRG(H1) "], v[26:27]\n\t" \
    "v_pk_fma_f32 v[28:29], v[" STRG(C0) ":" STRG(C1) "], v[" STRG(H0) ":" STRG(H1) "], v[28:29]\n\t" \
    "v_pk_fma_f32 v[30:31], v[" STRG(D0) ":" STRG(D1) "], v[" STRG(H0) ":" STRG(H1) "], v[30:31]\n\t"

__global__ __launch_bounds__(512) void k_lstm(const float* __restrict__ xpf,
                                              const float* __restrict__ xpb,
                                              const float* __restrict__ whf,
                                              const float* __restrict__ whb,
                                              float* __restrict__ out) {
    const int b = blockIdx.x;
    const int dir = blockIdx.y;
    const float* __restrict__ xp = dir ? xpb : xpf;
    const float* __restrict__ wh = dir ? whb : whf;
    const int t = threadIdx.x;  // 0..511
    const int q = t >> 2;       // unit 0..127
    const int jq = t & 3;       // h-col slice [32jq, 32jq+32)

    __shared__ __align__(1024) float h_lds[2][HH];
    if (t < HH) {
        h_lds[0][t] = 0.f;
        h_lds[1][t] = 0.f;
    }
    __syncthreads();

    unsigned hbase = (unsigned)(uintptr_t)&h_lds[0][0];
    unsigned rd0 = hbase + (unsigned)jq * 128u;          // read buffer 0
    unsigned rdd = rd0 ^ (rd0 + 512u);                   // XOR delta rd0<->rd1
    unsigned wr0 = hbase + 512u + ((unsigned)q << 2);    // first write -> buf 1
    unsigned wrd = wr0 ^ (wr0 - 512u);
    unsigned w0 = ((0u * 128u + (unsigned)q) * 128u + (unsigned)jq * 32u) * 4u;
    unsigned w1 = ((1u * 128u + (unsigned)q) * 128u + (unsigned)jq * 32u) * 4u;
    unsigned w2 = ((2u * 128u + (unsigned)q) * 128u + (unsigned)jq * 32u) * 4u;
    unsigned w3 = ((3u * 128u + (unsigned)q) * 128u + (unsigned)jq * 32u) * 4u;
    unsigned xoff = (unsigned)(b * 512 + t) * 4u + 16384u;  // prefetch = step 1
    float xp0v = xp[(size_t)b * 512 + t];
    float sel0 = (jq == 0) ? 1.f : 0.f;
    float sel1 = (jq == 1) ? 1.f : 0.f;
    float sel2 = (jq == 2) ? 1.f : 0.f;
    float sel3 = (jq == 3) ? 1.f : 0.f;
    float h_out;

    asm volatile(
        // ---- prologue: state init + 32x W dwordx4 loads (once) ----
        "v_mov_b32 v16, 0\n\t"        // c
        "v_mov_b32 v18, 0x800\n\t"    // counter = 2048
        "v_mov_b32 v19, %[x0]\n\t"    // xp current
        "v_mov_b32 v21, %[xo]\n\t"    // xp prefetch offset
        "v_mov_b32 v22, %[rdb]\n\t"   // ds read base
        "v_mov_b32 v23, %[wrb]\n\t"   // ds write addr
        WLD(64, 67, w0, 0) WLD(68, 71, w0, 16) WLD(72, 75, w0, 32) WLD(76, 79, w0, 48)
        WLD(80, 83, w0, 64) WLD(84, 87, w0, 80) WLD(88, 91, w0, 96) WLD(92, 95, w0, 112)
        WLD(96, 99, w1, 0) WLD(100, 103, w1, 16) WLD(104, 107, w1, 32) WLD(108, 111, w1, 48)
        WLD(112, 115, w1, 64) WLD(116, 119, w1, 80) WLD(120, 123, w1, 96) WLD(124, 127, w1, 112)
        WLD(128, 131, w2, 0) WLD(132, 135, w2, 16) WLD(136, 139, w2, 32) WLD(140, 143, w2, 48)
        WLD(144, 147, w2, 64) WLD(148, 151, w2, 80) WLD(152, 155, w2, 96) WLD(156, 159, w2, 112)
        WLD(160, 163, w3, 0) WLD(164, 167, w3, 16) WLD(168, 171, w3, 32) WLD(172, 175, w3, 48)
        WLD(176, 179, w3, 64) WLD(180, 183, w3, 80) WLD(184, 187, w3, 96) WLD(188, 191, w3, 112)
        "s_waitcnt vmcnt(0)\n\t"
        // ---- main loop ----
        "LSTM_TOP%=:\n\t"
        "global_load_dword v20, v21, %[xps]\n\t"  // prefetch xp step+1
        "ds_read_b128 v[32:35], v22\n\t"
        "ds_read_b128 v[36:39], v22 offset:16\n\t"
        "ds_read_b128 v[40:43], v22 offset:32\n\t"
        "ds_read_b128 v[44:47], v22 offset:48\n\t"
        "ds_read_b128 v[48:51], v22 offset:64\n\t"
        "ds_read_b128 v[52:55], v22 offset:80\n\t"
        "ds_read_b128 v[56:59], v22 offset:96\n\t"
        "ds_read_b128 v[60:63], v22 offset:112\n\t"
        // acc init = xp injected once per gate (lane jq)
        "v_mul_f32 v24, %[s0], v19\n\t"
        "v_mov_b32 v25, 0\n\t"
        "v_mul_f32 v26, %[s1], v19\n\t"
        "v_mov_b32 v27, 0\n\t"
        "v_mul_f32 v28, %[s2], v19\n\t"
        "v_mov_b32 v29, 0\n\t"
        "v_mul_f32 v30, %[s3], v19\n\t"
        "v_mov_b32 v31, 0\n\t"
        "s_waitcnt lgkmcnt(0)\n\t"
        // 64 packed-f32 FMAs: 4 gates x 16 pairs
        PKQ(32, 33, 64, 65, 96, 97, 128, 129, 160, 161)
        PKQ(34, 35, 66, 67, 98, 99, 130, 131, 162, 163)
        PKQ(36, 37, 68, 69, 100, 101, 132, 133, 164, 165)
        PKQ(38, 39, 70, 71, 102, 103, 134, 135, 166, 167)
        PKQ(40, 41, 72, 73, 104, 105, 136, 137, 168, 169)
        PKQ(42, 43, 74, 75, 106, 107, 138, 139, 170, 171)
        PKQ(44, 45, 76, 77, 108, 109, 140, 141, 172, 173)
        PKQ(46, 47, 78, 79, 110, 111, 142, 143, 174, 175)
        PKQ(48, 49, 80, 81, 112, 113, 144, 145, 176, 177)
        PKQ(50, 51, 82, 83, 114, 115, 146, 147, 178, 179)
        PKQ(52, 53, 84, 85, 116, 117, 148, 149, 180, 181)
        PKQ(54, 55, 86, 87, 118, 119, 150, 151, 182, 183)
        PKQ(56, 57, 88, 89, 120, 121, 152, 153, 184, 185)
        PKQ(58, 59, 90, 91, 122, 123, 154, 155, 186, 187)
        PKQ(60, 61, 92, 93, 124, 125, 156, 157, 188, 189)
        PKQ(62, 63, 94, 95, 126, 127, 158, 159, 190, 191)
        // horizontal add of packed halves
        "v_add_f32 v8, v24, v25\n\t"
        "v_add_f32 v9, v26, v27\n\t"
        "v_add_f32 v10, v28, v29\n\t"
        "v_add_f32 v11, v30, v31\n\t"
        // quad reduction: xor1 then xor2 (ds_swizzle butterfly)
        "ds_swizzle_b32 v12, v8 offset:0x041F\n\t"
        "ds_swizzle_b32 v13, v9 offset:0x041F\n\t"
        "ds_swizzle_b32 v14, v10 offset:0x041F\n\t"
        "ds_swizzle_b32 v15, v11 offset:0x041F\n\t"
        "s_waitcnt lgkmcnt(0)\n\t"
        "v_add_f32 v8, v8, v12\n\t"
        "v_add_f32 v9, v9, v13\n\t"
        "v_add_f32 v10, v10, v14\n\t"
        "v_add_f32 v11, v11, v15\n\t"
        "ds_swizzle_b32 v12, v8 offset:0x081F\n\t"
        "ds_swizzle_b32 v13, v9 offset:0x081F\n\t"
        "ds_swizzle_b32 v14, v10 offset:0x081F\n\t"
        "ds_swizzle_b32 v15, v11 offset:0x081F\n\t"
        "s_waitcnt lgkmcnt(0)\n\t"
        "v_add_f32 v8, v8, v12\n\t"
        "v_add_f32 v9, v9, v13\n\t"
        "v_add_f32 v10, v10, v14\n\t"
        "v_add_f32 v11, v11, v15\n\t"
        // activations, 4 chains interleaved (trans-use gaps >= 2):
        // sigma(x)=1/(1+2^(-x*log2e)); tanh(x)=2*sigma(2x)-1
        "v_mul_f32 v12, 0xbfb8aa3b, v8\n\t"   // -log2e * i
        "v_mul_f32 v13, 0xbfb8aa3b, v9\n\t"   // -log2e * f
        "v_mul_f32 v14, 0xc038aa3b, v10\n\t"  // -2log2e * g
        "v_mul_f32 v15, 0xbfb8aa3b, v11\n\t"  // -log2e * o
        "v_exp_f32 v12, v12\n\t"
        "v_exp_f32 v13, v13\n\t"
        "v_exp_f32 v14, v14\n\t"
        "v_exp_f32 v15, v15\n\t"
        "v_add_f32 v12, 1.0, v12\n\t"         // gap 3 from its exp
        "v_add_f32 v13, 1.0, v13\n\t"
        "v_add_f32 v14, 1.0, v14\n\t"
        "v_add_f32 v15, 1.0, v15\n\t"
        "v_rcp_f32 v12, v12\n\t"
        "v_rcp_f32 v13, v13\n\t"
        "v_rcp_f32 v14, v14\n\t"
        "v_rcp_f32 v15, v15\n\t"
        "s_nop 0\n\t"
        "v_fma_f32 v14, 2.0, v14, -1.0\n\t"   // tanh(g), gap 2 from rcp v14
        "v_mul_f32 v12, v12, v14\n\t"         // sig(i)*tanh(g), v12 gap 5
        "v_fma_f32 v16, v13, v16, v12\n\t"    // c = sig(f)*c + i*g, v13 gap 5
        "v_mul_f32 v14, 0xc038aa3b, v16\n\t"  // -2log2e * c
        "v_exp_f32 v14, v14\n\t"
        "s_nop 1\n\t"
        "v_add_f32 v14, 1.0, v14\n\t"
        "v_rcp_f32 v14, v14\n\t"
        "s_nop 1\n\t"
        "v_fma_f32 v14, 2.0, v14, -1.0\n\t"   // tanh(c)
        "v_mul_f32 v17, v14, v15\n\t"         // h = tanh(c)*sig(o), v15 gap big
        // publish h (all 4 quad lanes write identical value to same addr)
        "ds_write_b32 v23, v17\n\t"
        "s_waitcnt vmcnt(0) lgkmcnt(0)\n\t"
        "v_mov_b32 v19, v20\n\t"  // xpCur = prefetched
        "s_barrier\n\t"
        "v_add_u32 v18, -1, v18\n\t"
        "v_cmp_ne_u32 vcc, 0, v18\n\t"
        "v_xor_b32 v22, %[rdd], v22\n\t"  // swap read buffer
        "v_xor_b32 v23, %[wrd], v23\n\t"  // swap write buffer
        "v_add_u32 v21, 0x4000, v21\n\t"  // xp offset += 16KB
        "s_cbranch_vccnz LSTM_TOP%=\n\t"  // 3 instrs after v_cmp (vccz hazard)
        "v_mov_b32 %[ho], v17\n\t"
        : [ho] "=v"(h_out)
        : [w0] "v"(w0), [w1] "v"(w1), [w2] "v"(w2), [w3] "v"(w3),
          [whs] "s"(wh), [xps] "s"(xp),
          [xo] "v"(xoff), [rdb] "v"(rd0), [wrb] "v"(wr0),
          [rdd] "v"(rdd), [wrd] "v"(wrd), [x0] "v"(xp0v),
          [s0] "v"(sel0), [s1] "v"(sel1), [s2] "v"(sel2), [s3] "v"(sel3)
        : "memory", "vcc",
          "v8", "v9", "v10", "v11", "v12", "v13", "v14", "v15", "v16", "v17",
          "v18", "v19", "v20", "v21", "v22", "v23", "v24", "v25", "v26", "v27",
          "v28", "v29", "v30", "v31", "v32", "v33", "v34", "v35", "v36", "v37",
          "v38", "v39", "v40", "v41", "v42", "v43", "v44", "v45", "v46", "v47",
          "v48", "v49", "v50", "v51", "v52", "v53", "v54", "v55", "v56", "v57",
          "v58", "v59", "v60", "v61", "v62", "v63", "v64", "v65", "v66", "v67",
          "v68", "v69", "v70", "v71", "v72", "v73", "v74", "v75", "v76", "v77",
          "v78", "v79", "v80", "v81", "v82", "v83", "v84", "v85", "v86", "v87",
          "v88", "v89", "v90", "v91", "v92", "v93", "v94", "v95", "v96", "v97",
          "v98", "v99", "v100", "v101", "v102", "v103", "v104", "v105", "v106", "v107",
          "v108", "v109", "v110", "v111", "v112", "v113", "v114", "v115", "v116", "v117",
          "v118", "v119", "v120", "v121", "v122", "v123", "v124", "v125", "v126", "v127",
          "v128", "v129", "v130", "v131", "v132", "v133", "v134", "v135", "v136", "v137",
          "v138", "v139", "v140", "v141", "v142", "v143", "v144", "v145", "v146", "v147",
          "v148", "v149", "v150", "v151", "v152", "v153", "v154", "v155", "v156", "v157",
          "v158", "v159", "v160", "v161", "v162", "v163", "v164", "v165", "v166", "v167",
          "v168", "v169", "v170", "v171", "v172", "v173", "v174", "v175", "v176", "v177",
          "v178", "v179", "v180", "v181", "v182", "v183", "v184", "v185", "v186", "v187",
          "v188", "v189", "v190", "v191");

    if (jq == 0) out[(size_t)b * 256 + dir * HH + q] = h_out;
}

extern "C" void kernel_launch(void* const* d_in, const int* in_sizes, int n_in,
                              void* d_out, int out_size, void* d_ws, size_t ws_size,
                              hipStream_t stream) {
    const float* x = (const float*)d_in[0];
    const int* adj = (const int*)d_in[1];
    const float* wif = (const float*)d_in[2];
    const float* whf = (const float*)d_in[3];
    const float* bif = (const float*)d_in[4];
    const float* bhf = (const float*)d_in[5];
    const float* wib = (const float*)d_in[6];
    const float* whb = (const float*)d_in[7];
    const float* bib = (const float*)d_in[8];
    const float* bhb = (const float*)d_in[9];
    float* out = (float*)d_out;

    // Layout: xpf | xpb | xa  (so the last-iteration xp prefetch overrun of
    // +16KB from either xp region lands in mapped scratch).
    float* xpf = (float*)d_ws;                 // [N][B][512]
    float* xpb = xpf + (size_t)NN * BB * 512;  // [N][B][512]
    float* xa = xpb + (size_t)NN * BB * 512;   // [B][N][D]

    k_agg<<<dim3(NN / TI, BB), 256, 0, stream>>>(x, adj, xa);
    k_proj<<<dim3((NN * BB) / MT, 1024 / GT), 256, 0, stream>>>(xa, wif, wib, bif, bhf, bib, bhb,
                                                                xpf, xpb);
    k_lstm<<<dim3(BB, 2), 512, 0, stream>>>(xpf, xpb, whf, whb, out);
}

// Round 11
// 1469.459 us; speedup vs baseline: 40.1694x; 1.1646x over previous
//
#include <hip/hip_runtime.h>
#include <math.h>

#define BB 8
#define NN 2048
#define DD 128
#define HH 128

typedef float f4 __attribute__((ext_vector_type(4)));

__device__ __forceinline__ float fast_rcp(float x) { return __builtin_amdgcn_rcpf(x); }

// ---------------- Kernel 1: graph aggregation ----------------
#define TI 32
#define TJ 64

__global__ __launch_bounds__(256) void k_agg(const float* __restrict__ x,
                                             const int* __restrict__ adj,
                                             float* __restrict__ xa) {
    __shared__ __align__(16) float xs[TJ][132];
    __shared__ __align__(16) float as[TI][68];
    const int b = blockIdx.y;
    const int i0 = blockIdx.x * TI;
    const int tid = threadIdx.x;
    const int ig = tid >> 5;
    const int dg = tid & 31;
    const float* xb = x + (size_t)b * NN * DD;
    const int* ab = adj + (size_t)b * NN * NN;

    float acc[4][4];
    float deg[4];
#pragma unroll
    for (int i = 0; i < 4; ++i) {
        deg[i] = 0.f;
#pragma unroll
        for (int d = 0; d < 4; ++d) acc[i][d] = 0.f;
    }

    for (int j0 = 0; j0 < NN; j0 += TJ) {
#pragma unroll
        for (int k = 0; k < 8; ++k) {
            int idx = tid + k * 256;
            int row = idx >> 5, c4 = idx & 31;
            float4 v = *(const float4*)(xb + (size_t)(j0 + row) * DD + c4 * 4);
            *(float4*)(&xs[row][c4 * 4]) = v;
        }
#pragma unroll
        for (int k = 0; k < 2; ++k) {
            int idx = tid + k * 256;
            int row = idx >> 4, c4 = idx & 15;
            int4 v = *(const int4*)(ab + (size_t)(i0 + row) * NN + j0 + c4 * 4);
            float4 f;
            f.x = v.x > 0 ? 1.f : 0.f;
            f.y = v.y > 0 ? 1.f : 0.f;
            f.z = v.z > 0 ? 1.f : 0.f;
            f.w = v.w > 0 ? 1.f : 0.f;
            *(float4*)(&as[row][c4 * 4]) = f;
        }
        __syncthreads();
#pragma unroll 4
        for (int jq = 0; jq < TJ; jq += 4) {
            float4 av[4], xv[4];
#pragma unroll
            for (int i = 0; i < 4; ++i) av[i] = *(const float4*)(&as[ig * 4 + i][jq]);
#pragma unroll
            for (int jj = 0; jj < 4; ++jj) xv[jj] = *(const float4*)(&xs[jq + jj][dg * 4]);
#pragma unroll
            for (int i = 0; i < 4; ++i) {
                const float* ap = (const float*)&av[i];
#pragma unroll
                for (int jj = 0; jj < 4; ++jj) {
                    float a = ap[jj];
                    const float* xp4 = (const float*)&xv[jj];
                    deg[i] += a;
                    acc[i][0] = fmaf(a, xp4[0], acc[i][0]);
                    acc[i][1] = fmaf(a, xp4[1], acc[i][1]);
                    acc[i][2] = fmaf(a, xp4[2], acc[i][2]);
                    acc[i][3] = fmaf(a, xp4[3], acc[i][3]);
                }
            }
        }
        __syncthreads();
    }
#pragma unroll
    for (int i = 0; i < 4; ++i) {
        int gi = i0 + ig * 4 + i;
        float r = fast_rcp(1.f + deg[i]);
        float4 xv = *(const float4*)(xb + (size_t)gi * DD + dg * 4);
        float4 o;
        o.x = (xv.x + acc[i][0]) * r;
        o.y = (xv.y + acc[i][1]) * r;
        o.z = (xv.z + acc[i][2]) * r;
        o.w = (xv.w + acc[i][3]) * r;
        *(float4*)(xa + ((size_t)b * NN + gi) * DD + dg * 4) = o;
    }
}

// ---------------- Kernel 2: input projection (both dirs) ----------------
// Writes xp pre-permuted for k_lstm: gate (unit u, type j) -> slot 4*u+j.
// Backward dir also pre-reversed in time.
#define MT 64
#define GT 32

__global__ __launch_bounds__(256) void k_proj(const float* __restrict__ xa,
                                              const float* __restrict__ wif,
                                              const float* __restrict__ wib,
                                              const float* __restrict__ bif,
                                              const float* __restrict__ bhf,
                                              const float* __restrict__ bib,
                                              const float* __restrict__ bhb,
                                              float* __restrict__ xpf,
                                              float* __restrict__ xpb) {
    __shared__ __align__(16) float xs[MT][132];
    __shared__ __align__(16) float wl[GT][132];
    const int r0 = blockIdx.x * MT;
    const int g0 = blockIdx.y * GT;
    const int tid = threadIdx.x;
#pragma unroll
    for (int k = 0; k < 8; ++k) {
        int idx = tid + k * 256;
        int row = idx >> 5, c4 = idx & 31;
        int r = r0 + row;
        int t = r >> 3, bb = r & 7;
        float4 v = *(const float4*)(xa + ((size_t)bb * NN + t) * DD + c4 * 4);
        *(float4*)(&xs[row][c4 * 4]) = v;
    }
#pragma unroll
    for (int k = 0; k < 4; ++k) {
        int idx = tid + k * 256;
        int row = idx >> 5, c4 = idx & 31;
        int g = g0 + row;
        const float* wsrc = (g < 512) ? (wif + (size_t)g * DD) : (wib + (size_t)(g - 512) * DD);
        *(float4*)(&wl[row][c4 * 4]) = *(const float4*)(wsrc + c4 * 4);
    }
    __syncthreads();
    const int mg = tid >> 4;
    const int gg = tid & 15;
    float acc[4][2];
#pragma unroll
    for (int i = 0; i < 4; ++i) { acc[i][0] = 0.f; acc[i][1] = 0.f; }
#pragma unroll 8
    for (int d4 = 0; d4 < 32; ++d4) {
        float4 xv[4], wv[2];
#pragma unroll
        for (int i = 0; i < 4; ++i) xv[i] = *(const float4*)(&xs[mg * 4 + i][d4 * 4]);
        wv[0] = *(const float4*)(&wl[gg * 2 + 0][d4 * 4]);
        wv[1] = *(const float4*)(&wl[gg * 2 + 1][d4 * 4]);
#pragma unroll
        for (int i = 0; i < 4; ++i) {
#pragma unroll
            for (int j = 0; j < 2; ++j) {
                acc[i][j] = fmaf(xv[i].x, wv[j].x, acc[i][j]);
                acc[i][j] = fmaf(xv[i].y, wv[j].y, acc[i][j]);
                acc[i][j] = fmaf(xv[i].z, wv[j].z, acc[i][j]);
                acc[i][j] = fmaf(xv[i].w, wv[j].w, acc[i][j]);
            }
        }
    }
#pragma unroll
    for (int j = 0; j < 2; ++j) {
        int g = g0 + gg * 2 + j;
        float bias = (g < 512) ? (bif[g] + bhf[g]) : (bib[g - 512] + bhb[g - 512]);
#pragma unroll
        for (int i = 0; i < 4; ++i) {
            int r = r0 + mg * 4 + i;
            int t = r >> 3, bb = r & 7;
            float v = acc[i][j] + bias;
            if (g < 512) {
                int p = 4 * (g & 127) + (g >> 7);
                xpf[((size_t)t * BB + bb) * 512 + p] = v;
            } else {
                int gb = g - 512;
                int p = 4 * (gb & 127) + (gb >> 7);
                xpb[((size_t)(NN - 1 - t) * BB + bb) * 512 + p] = v;
            }
        }
    }
}

// ---------------- Kernel 3: LSTM recurrence (full inline-asm loop) ---------
// One block per (batch,dir), 512 threads. Quad q owns unit q; lane jq covers
// h-cols [32jq,32jq+32) for all 4 gate types. v8-v31 temps/accs, v32-v63 h,
// v64-v191 W (loaded once).
// R10 lessons fixed here:
//  * LDS h kept in 4 REPLICAS (stride 544B): lane jq writes h[q] to replica jq
//    (2-way write conflict = free) and reads slice jq from replica jq at base
//    672*jq (bank quads {0,8,16,24}+4k -> conflict-free reads).
//  * quad-reduce via v_mov_b32_dpp quad_perm butterflies (pure VALU, no LDS,
//    no lgkm waits). Write->DPP-read gaps >= 3 instructions everywhere.

#define STRG(x) #x
#define WLD(R0, R3, WOFF, IMM)                                            \
    "global_load_dwordx4 v[" STRG(R0) ":" STRG(R3) "], %[" STRG(WOFF) "], %[whs] offset:" STRG(IMM) "\n\t"
#define PKQ(H0, H1, A0, A1, B0, B1, C0, C1, D0, D1)                                        \
    "v_pk_fma_f32 v[24:25], v[" STRG(A0) ":" STRG(A1) "], v[" STRG(H0) ":" STRG(H1) "], v[24:25]\n\t" \
    "v_pk_fma_f32 v[26:27], v[" STRG(B0) ":" STRG(B1) "], v[" STRG(H0) ":" STRG(H1) "], v[26:27]\n\t" \
    "v_pk_fma_f32 v[28:29], v[" STRG(C0) ":" STRG(C1) "], v[" STRG(H0) ":" STRG(H1) "], v[28:29]\n\t" \
    "v_pk_fma_f32 v[30:31], v[" STRG(D0) ":" STRG(D1) "], v[" STRG(H0) ":" STRG(H1) "], v[30:31]\n\t"

__global__ __launch_bounds__(512) void k_lstm(const float* __restrict__ xpf,
                                              const float* __restrict__ xpb,
                                              const float* __restrict__ whf,
                                              const float* __restrict__ whb,
                                              float* __restrict__ out) {
    const int b = blockIdx.x;
    const int dir = blockIdx.y;
    const float* __restrict__ xp = dir ? xpb : xpf;
    const float* __restrict__ wh = dir ? whb : whf;
    const int t = threadIdx.x;  // 0..511
    const int q = t >> 2;       // unit 0..127
    const int jq = t & 3;       // h-col slice [32jq, 32jq+32)

    // Two buffers of 4 h-replicas each. Replica stride 544 B, buffer stride
    // 2176 B, total 4352 B.
    __shared__ __align__(64) float h_lds[1088];
    for (int i = t; i < 1088; i += 512) h_lds[i] = 0.f;
    __syncthreads();

    unsigned hbase = (unsigned)(uintptr_t)&h_lds[0];
    unsigned rd0 = hbase + 672u * (unsigned)jq;                         // replica jq, slice jq
    unsigned rdd = rd0 ^ (rd0 + 2176u);                                 // buffer toggle
    unsigned wr0 = hbase + 2176u + 544u * (unsigned)jq + ((unsigned)q << 2);  // first write -> buf 1
    unsigned wrd = wr0 ^ (wr0 - 2176u);
    unsigned w0 = ((0u * 128u + (unsigned)q) * 128u + (unsigned)jq * 32u) * 4u;
    unsigned w1 = ((1u * 128u + (unsigned)q) * 128u + (unsigned)jq * 32u) * 4u;
    unsigned w2 = ((2u * 128u + (unsigned)q) * 128u + (unsigned)jq * 32u) * 4u;
    unsigned w3 = ((3u * 128u + (unsigned)q) * 128u + (unsigned)jq * 32u) * 4u;
    unsigned xoff = (unsigned)(b * 512 + t) * 4u + 16384u;  // prefetch = step 1
    float xp0v = xp[(size_t)b * 512 + t];
    float sel0 = (jq == 0) ? 1.f : 0.f;
    float sel1 = (jq == 1) ? 1.f : 0.f;
    float sel2 = (jq == 2) ? 1.f : 0.f;
    float sel3 = (jq == 3) ? 1.f : 0.f;
    float h_out;

    asm volatile(
        // ---- prologue: state init + 32x W dwordx4 loads (once) ----
        "v_mov_b32 v16, 0\n\t"        // c
        "v_mov_b32 v18, 0x800\n\t"    // counter = 2048
        "v_mov_b32 v19, %[x0]\n\t"    // xp current
        "v_mov_b32 v21, %[xo]\n\t"    // xp prefetch offset
        "v_mov_b32 v22, %[rdb]\n\t"   // ds read base
        "v_mov_b32 v23, %[wrb]\n\t"   // ds write addr
        WLD(64, 67, w0, 0) WLD(68, 71, w0, 16) WLD(72, 75, w0, 32) WLD(76, 79, w0, 48)
        WLD(80, 83, w0, 64) WLD(84, 87, w0, 80) WLD(88, 91, w0, 96) WLD(92, 95, w0, 112)
        WLD(96, 99, w1, 0) WLD(100, 103, w1, 16) WLD(104, 107, w1, 32) WLD(108, 111, w1, 48)
        WLD(112, 115, w1, 64) WLD(116, 119, w1, 80) WLD(120, 123, w1, 96) WLD(124, 127, w1, 112)
        WLD(128, 131, w2, 0) WLD(132, 135, w2, 16) WLD(136, 139, w2, 32) WLD(140, 143, w2, 48)
        WLD(144, 147, w2, 64) WLD(148, 151, w2, 80) WLD(152, 155, w2, 96) WLD(156, 159, w2, 112)
        WLD(160, 163, w3, 0) WLD(164, 167, w3, 16) WLD(168, 171, w3, 32) WLD(172, 175, w3, 48)
        WLD(176, 179, w3, 64) WLD(180, 183, w3, 80) WLD(184, 187, w3, 96) WLD(188, 191, w3, 112)
        "s_waitcnt vmcnt(0)\n\t"
        // ---- main loop ----
        "LSTM_TOP%=:\n\t"
        "global_load_dword v20, v21, %[xps]\n\t"  // prefetch xp step+1
        "ds_read_b128 v[32:35], v22\n\t"
        "ds_read_b128 v[36:39], v22 offset:16\n\t"
        "ds_read_b128 v[40:43], v22 offset:32\n\t"
        "ds_read_b128 v[44:47], v22 offset:48\n\t"
        "ds_read_b128 v[48:51], v22 offset:64\n\t"
        "ds_read_b128 v[52:55], v22 offset:80\n\t"
        "ds_read_b128 v[56:59], v22 offset:96\n\t"
        "ds_read_b128 v[60:63], v22 offset:112\n\t"
        // acc init = xp injected once per gate (lane jq)
        "v_mul_f32 v24, %[s0], v19\n\t"
        "v_mov_b32 v25, 0\n\t"
        "v_mul_f32 v26, %[s1], v19\n\t"
        "v_mov_b32 v27, 0\n\t"
        "v_mul_f32 v28, %[s2], v19\n\t"
        "v_mov_b32 v29, 0\n\t"
        "v_mul_f32 v30, %[s3], v19\n\t"
        "v_mov_b32 v31, 0\n\t"
        "s_waitcnt lgkmcnt(0)\n\t"
        // 64 packed-f32 FMAs: 4 gates x 16 pairs
        PKQ(32, 33, 64, 65, 96, 97, 128, 129, 160, 161)
        PKQ(34, 35, 66, 67, 98, 99, 130, 131, 162, 163)
        PKQ(36, 37, 68, 69, 100, 101, 132, 133, 164, 165)
        PKQ(38, 39, 70, 71, 102, 103, 134, 135, 166, 167)
        PKQ(40, 41, 72, 73, 104, 105, 136, 137, 168, 169)
        PKQ(42, 43, 74, 75, 106, 107, 138, 139, 170, 171)
        PKQ(44, 45, 76, 77, 108, 109, 140, 141, 172, 173)
        PKQ(46, 47, 78, 79, 110, 111, 142, 143, 174, 175)
        PKQ(48, 49, 80, 81, 112, 113, 144, 145, 176, 177)
        PKQ(50, 51, 82, 83, 114, 115, 146, 147, 178, 179)
        PKQ(52, 53, 84, 85, 116, 117, 148, 149, 180, 181)
        PKQ(54, 55, 86, 87, 118, 119, 150, 151, 182, 183)
        PKQ(56, 57, 88, 89, 120, 121, 152, 153, 184, 185)
        PKQ(58, 59, 90, 91, 122, 123, 154, 155, 186, 187)
        PKQ(60, 61, 92, 93, 124, 125, 156, 157, 188, 189)
        PKQ(62, 63, 94, 95, 126, 127, 158, 159, 190, 191)
        // horizontal add of packed halves
        "v_add_f32 v8, v24, v25\n\t"
        "v_add_f32 v9, v26, v27\n\t"
        "v_add_f32 v10, v28, v29\n\t"
        "v_add_f32 v11, v30, v31\n\t"
        // quad reduction via DPP butterflies (no LDS, no waits)
        "v_mov_b32_dpp v12, v8 quad_perm:[1,0,3,2] row_mask:0xf bank_mask:0xf\n\t"
        "v_mov_b32_dpp v13, v9 quad_perm:[1,0,3,2] row_mask:0xf bank_mask:0xf\n\t"
        "v_mov_b32_dpp v14, v10 quad_perm:[1,0,3,2] row_mask:0xf bank_mask:0xf\n\t"
        "v_mov_b32_dpp v15, v11 quad_perm:[1,0,3,2] row_mask:0xf bank_mask:0xf\n\t"
        "v_add_f32 v8, v8, v12\n\t"
        "v_add_f32 v9, v9, v13\n\t"
        "v_add_f32 v10, v10, v14\n\t"
        "v_add_f32 v11, v11, v15\n\t"
        "v_mov_b32_dpp v12, v8 quad_perm:[2,3,0,1] row_mask:0xf bank_mask:0xf\n\t"
        "v_mov_b32_dpp v13, v9 quad_perm:[2,3,0,1] row_mask:0xf bank_mask:0xf\n\t"
        "v_mov_b32_dpp v14, v10 quad_perm:[2,3,0,1] row_mask:0xf bank_mask:0xf\n\t"
        "v_mov_b32_dpp v15, v11 quad_perm:[2,3,0,1] row_mask:0xf bank_mask:0xf\n\t"
        "v_add_f32 v8, v8, v12\n\t"
        "v_add_f32 v9, v9, v13\n\t"
        "v_add_f32 v10, v10, v14\n\t"
        "v_add_f32 v11, v11, v15\n\t"
        // activations, 4 chains interleaved (trans-use gaps >= 2):
        // sigma(x)=1/(1+2^(-x*log2e)); tanh(x)=2*sigma(2x)-1
        "v_mul_f32 v12, 0xbfb8aa3b, v8\n\t"   // -log2e * i
        "v_mul_f32 v13, 0xbfb8aa3b, v9\n\t"   // -log2e * f
        "v_mul_f32 v14, 0xc038aa3b, v10\n\t"  // -2log2e * g
        "v_mul_f32 v15, 0xbfb8aa3b, v11\n\t"  // -log2e * o
        "v_exp_f32 v12, v12\n\t"
        "v_exp_f32 v13, v13\n\t"
        "v_exp_f32 v14, v14\n\t"
        "v_exp_f32 v15, v15\n\t"
        "v_add_f32 v12, 1.0, v12\n\t"         // gap 3 from its exp
        "v_add_f32 v13, 1.0, v13\n\t"
        "v_add_f32 v14, 1.0, v14\n\t"
        "v_add_f32 v15, 1.0, v15\n\t"
        "v_rcp_f32 v12, v12\n\t"
        "v_rcp_f32 v13, v13\n\t"
        "v_rcp_f32 v14, v14\n\t"
        "v_rcp_f32 v15, v15\n\t"
        "s_nop 0\n\t"
        "v_fma_f32 v14, 2.0, v14, -1.0\n\t"   // tanh(g), gap 2 from rcp v14
        "v_mul_f32 v12, v12, v14\n\t"         // sig(i)*tanh(g), v12 gap 5
        "v_fma_f32 v16, v13, v16, v12\n\t"    // c = sig(f)*c + i*g, v13 gap 5
        "v_mul_f32 v14, 0xc038aa3b, v16\n\t"  // -2log2e * c
        "v_exp_f32 v14, v14\n\t"
        "s_nop 1\n\t"
        "v_add_f32 v14, 1.0, v14\n\t"
        "v_rcp_f32 v14, v14\n\t"
        "s_nop 1\n\t"
        "v_fma_f32 v14, 2.0, v14, -1.0\n\t"   // tanh(c)
        "v_mul_f32 v17, v14, v15\n\t"         // h = tanh(c)*sig(o)
        // publish h: lane jq writes replica jq (distinct addrs, 2-way free)
        "ds_write_b32 v23, v17\n\t"
        "s_waitcnt vmcnt(0) lgkmcnt(0)\n\t"
        "v_mov_b32 v19, v20\n\t"  // xpCur = prefetched
        "s_barrier\n\t"
        "v_add_u32 v18, -1, v18\n\t"
        "v_cmp_ne_u32 vcc, 0, v18\n\t"
        "v_xor_b32 v22, %[rdd], v22\n\t"  // swap read buffer
        "v_xor_b32 v23, %[wrd], v23\n\t"  // swap write buffer
        "v_add_u32 v21, 0x4000, v21\n\t"  // xp offset += 16KB
        "s_cbranch_vccnz LSTM_TOP%=\n\t"  // 3 instrs after v_cmp (vccz hazard)
        "v_mov_b32 %[ho], v17\n\t"
        : [ho] "=v"(h_out)
        : [w0] "v"(w0), [w1] "v"(w1), [w2] "v"(w2), [w3] "v"(w3),
          [whs] "s"(wh), [xps] "s"(xp),
          [xo] "v"(xoff), [rdb] "v"(rd0), [wrb] "v"(wr0),
          [rdd] "v"(rdd), [wrd] "v"(wrd), [x0] "v"(xp0v),
          [s0] "v"(sel0), [s1] "v"(sel1), [s2] "v"(sel2), [s3] "v"(sel3)
        : "memory", "vcc",
          "v8", "v9", "v10", "v11", "v12", "v13", "v14", "v15", "v16", "v17",
          "v18", "v19", "v20", "v21", "v22", "v23", "v24", "v25", "v26", "v27",
          "v28", "v29", "v30", "v31", "v32", "v33", "v34", "v35", "v36", "v37",
          "v38", "v39", "v40", "v41", "v42", "v43", "v44", "v45", "v46", "v47",
          "v48", "v49", "v50", "v51", "v52", "v53", "v54", "v55", "v56", "v57",
          "v58", "v59", "v60", "v61", "v62", "v63", "v64", "v65", "v66", "v67",
          "v68", "v69", "v70", "v71", "v72", "v73", "v74", "v75", "v76", "v77",
          "v78", "v79", "v80", "v81", "v82", "v83", "v84", "v85", "v86", "v87",
          "v88", "v89", "v90", "v91", "v92", "v93", "v94", "v95", "v96", "v97",
          "v98", "v99", "v100", "v101", "v102", "v103", "v104", "v105", "v106", "v107",
          "v108", "v109", "v110", "v111", "v112", "v113", "v114", "v115", "v116", "v117",
          "v118", "v119", "v120", "v121", "v122", "v123", "v124", "v125", "v126", "v127",
          "v128", "v129", "v130", "v131", "v132", "v133", "v134", "v135", "v136", "v137",
          "v138", "v139", "v140", "v141", "v142", "v143", "v144", "v145", "v146", "v147",
          "v148", "v149", "v150", "v151", "v152", "v153", "v154", "v155", "v156", "v157",
          "v158", "v159", "v160", "v161", "v162", "v163", "v164", "v165", "v166", "v167",
          "v168", "v169", "v170", "v171", "v172", "v173", "v174", "v175", "v176", "v177",
          "v178", "v179", "v180", "v181", "v182", "v183", "v184", "v185", "v186", "v187",
          "v188", "v189", "v190", "v191");

    if (jq == 0) out[(size_t)b * 256 + dir * HH + q] = h_out;
}

extern "C" void kernel_launch(void* const* d_in, const int* in_sizes, int n_in,
                              void* d_out, int out_size, void* d_ws, size_t ws_size,
                              hipStream_t stream) {
    const float* x = (const float*)d_in[0];
    const int* adj = (const int*)d_in[1];
    const float* wif = (const float*)d_in[2];
    const float* whf = (const float*)d_in[3];
    const float* bif = (const float*)d_in[4];
    const float* bhf = (const float*)d_in[5];
    const float* wib = (const float*)d_in[6];
    const float* whb = (const float*)d_in[7];
    const float* bib = (const float*)d_in[8];
    const float* bhb = (const float*)d_in[9];
    float* out = (float*)d_out;

    // Layout: xpf | xpb | xa  (so the last-iteration xp prefetch overrun of
    // +16KB from either xp region lands in mapped scratch).
    float* xpf = (float*)d_ws;                 // [N][B][512]
    float* xpb = xpf + (size_t)NN * BB * 512;  // [N][B][512]
    float* xa = xpb + (size_t)NN * BB * 512;   // [B][N][D]

    k_agg<<<dim3(NN / TI, BB), 256, 0, stream>>>(x, adj, xa);
    k_proj<<<dim3((NN * BB) / MT, 1024 / GT), 256, 0, stream>>>(xa, wif, wib, bif, bhf, bib, bhb,
                                                                xpf, xpb);
    k_lstm<<<dim3(BB, 2), 512, 0, stream>>>(xpf, xpb, whf, whb, out);
}

// Round 12
// 1363.029 us; speedup vs baseline: 43.3060x; 1.0781x over previous
//
#include <hip/hip_runtime.h>
#include <math.h>

#define BB 8
#define NN 2048
#define DD 128
#define HH 128

typedef float f4 __attribute__((ext_vector_type(4)));

__device__ __forceinline__ float fast_rcp(float x) { return __builtin_amdgcn_rcpf(x); }

// ---------------- Kernel 1: graph aggregation ----------------
#define TI 32
#define TJ 64

__global__ __launch_bounds__(256) void k_agg(const float* __restrict__ x,
                                             const int* __restrict__ adj,
                                             float* __restrict__ xa) {
    __shared__ __align__(16) float xs[TJ][132];
    __shared__ __align__(16) float as[TI][68];
    const int b = blockIdx.y;
    const int i0 = blockIdx.x * TI;
    const int tid = threadIdx.x;
    const int ig = tid >> 5;
    const int dg = tid & 31;
    const float* xb = x + (size_t)b * NN * DD;
    const int* ab = adj + (size_t)b * NN * NN;

    float acc[4][4];
    float deg[4];
#pragma unroll
    for (int i = 0; i < 4; ++i) {
        deg[i] = 0.f;
#pragma unroll
        for (int d = 0; d < 4; ++d) acc[i][d] = 0.f;
    }

    for (int j0 = 0; j0 < NN; j0 += TJ) {
#pragma unroll
        for (int k = 0; k < 8; ++k) {
            int idx = tid + k * 256;
            int row = idx >> 5, c4 = idx & 31;
            float4 v = *(const float4*)(xb + (size_t)(j0 + row) * DD + c4 * 4);
            *(float4*)(&xs[row][c4 * 4]) = v;
        }
#pragma unroll
        for (int k = 0; k < 2; ++k) {
            int idx = tid + k * 256;
            int row = idx >> 4, c4 = idx & 15;
            int4 v = *(const int4*)(ab + (size_t)(i0 + row) * NN + j0 + c4 * 4);
            float4 f;
            f.x = v.x > 0 ? 1.f : 0.f;
            f.y = v.y > 0 ? 1.f : 0.f;
            f.z = v.z > 0 ? 1.f : 0.f;
            f.w = v.w > 0 ? 1.f : 0.f;
            *(float4*)(&as[row][c4 * 4]) = f;
        }
        __syncthreads();
#pragma unroll 4
        for (int jq = 0; jq < TJ; jq += 4) {
            float4 av[4], xv[4];
#pragma unroll
            for (int i = 0; i < 4; ++i) av[i] = *(const float4*)(&as[ig * 4 + i][jq]);
#pragma unroll
            for (int jj = 0; jj < 4; ++jj) xv[jj] = *(const float4*)(&xs[jq + jj][dg * 4]);
#pragma unroll
            for (int i = 0; i < 4; ++i) {
                const float* ap = (const float*)&av[i];
#pragma unroll
                for (int jj = 0; jj < 4; ++jj) {
                    float a = ap[jj];
                    const float* xp4 = (const float*)&xv[jj];
                    deg[i] += a;
                    acc[i][0] = fmaf(a, xp4[0], acc[i][0]);
                    acc[i][1] = fmaf(a, xp4[1], acc[i][1]);
                    acc[i][2] = fmaf(a, xp4[2], acc[i][2]);
                    acc[i][3] = fmaf(a, xp4[3], acc[i][3]);
                }
            }
        }
        __syncthreads();
    }
#pragma unroll
    for (int i = 0; i < 4; ++i) {
        int gi = i0 + ig * 4 + i;
        float r = fast_rcp(1.f + deg[i]);
        float4 xv = *(const float4*)(xb + (size_t)gi * DD + dg * 4);
        float4 o;
        o.x = (xv.x + acc[i][0]) * r;
        o.y = (xv.y + acc[i][1]) * r;
        o.z = (xv.z + acc[i][2]) * r;
        o.w = (xv.w + acc[i][3]) * r;
        *(float4*)(xa + ((size_t)b * NN + gi) * DD + dg * 4) = o;
    }
}

// ---------------- Kernel 2: input projection (both dirs) ----------------
// Writes xp pre-permuted for k_lstm: gate (unit u, type j) -> slot 4*u+j.
// Backward dir also pre-reversed in time.
#define MT 64
#define GT 32

__global__ __launch_bounds__(256) void k_proj(const float* __restrict__ xa,
                                              const float* __restrict__ wif,
                                              const float* __restrict__ wib,
                                              const float* __restrict__ bif,
                                              const float* __restrict__ bhf,
                                              const float* __restrict__ bib,
                                              const float* __restrict__ bhb,
                                              float* __restrict__ xpf,
                                              float* __restrict__ xpb) {
    __shared__ __align__(16) float xs[MT][132];
    __shared__ __align__(16) float wl[GT][132];
    const int r0 = blockIdx.x * MT;
    const int g0 = blockIdx.y * GT;
    const int tid = threadIdx.x;
#pragma unroll
    for (int k = 0; k < 8; ++k) {
        int idx = tid + k * 256;
        int row = idx >> 5, c4 = idx & 31;
        int r = r0 + row;
        int t = r >> 3, bb = r & 7;
        float4 v = *(const float4*)(xa + ((size_t)bb * NN + t) * DD + c4 * 4);
        *(float4*)(&xs[row][c4 * 4]) = v;
    }
#pragma unroll
    for (int k = 0; k < 4; ++k) {
        int idx = tid + k * 256;
        int row = idx >> 5, c4 = idx & 31;
        int g = g0 + row;
        const float* wsrc = (g < 512) ? (wif + (size_t)g * DD) : (wib + (size_t)(g - 512) * DD);
        *(float4*)(&wl[row][c4 * 4]) = *(const float4*)(wsrc + c4 * 4);
    }
    __syncthreads();
    const int mg = tid >> 4;
    const int gg = tid & 15;
    float acc[4][2];
#pragma unroll
    for (int i = 0; i < 4; ++i) { acc[i][0] = 0.f; acc[i][1] = 0.f; }
#pragma unroll 8
    for (int d4 = 0; d4 < 32; ++d4) {
        float4 xv[4], wv[2];
#pragma unroll
        for (int i = 0; i < 4; ++i) xv[i] = *(const float4*)(&xs[mg * 4 + i][d4 * 4]);
        wv[0] = *(const float4*)(&wl[gg * 2 + 0][d4 * 4]);
        wv[1] = *(const float4*)(&wl[gg * 2 + 1][d4 * 4]);
#pragma unroll
        for (int i = 0; i < 4; ++i) {
#pragma unroll
            for (int j = 0; j < 2; ++j) {
                acc[i][j] = fmaf(xv[i].x, wv[j].x, acc[i][j]);
                acc[i][j] = fmaf(xv[i].y, wv[j].y, acc[i][j]);
                acc[i][j] = fmaf(xv[i].z, wv[j].z, acc[i][j]);
                acc[i][j] = fmaf(xv[i].w, wv[j].w, acc[i][j]);
            }
        }
    }
#pragma unroll
    for (int j = 0; j < 2; ++j) {
        int g = g0 + gg * 2 + j;
        float bias = (g < 512) ? (bif[g] + bhf[g]) : (bib[g - 512] + bhb[g - 512]);
#pragma unroll
        for (int i = 0; i < 4; ++i) {
            int r = r0 + mg * 4 + i;
            int t = r >> 3, bb = r & 7;
            float v = acc[i][j] + bias;
            if (g < 512) {
                int p = 4 * (g & 127) + (g >> 7);
                xpf[((size_t)t * BB + bb) * 512 + p] = v;
            } else {
                int gb = g - 512;
                int p = 4 * (gb & 127) + (gb >> 7);
                xpb[((size_t)(NN - 1 - t) * BB + bb) * 512 + p] = v;
            }
        }
    }
}

// ---------------- Kernel 3: LSTM recurrence (full inline-asm loop) ---------
// One block per (batch,dir), 512 threads. Quad q owns unit q; lane jq covers
// h-cols [32jq,32jq+32) for all 4 gate types. v8-v31 temps/accs, v32-v63 h,
// v64-v191 W (loaded once). Replica-padded LDS (R11, conflict-free).
// R12 changes (issue/stall trim):
//  * chunked s_waitcnt lgkmcnt(7-k): FMAs on chunk k start when its read lands
//  * accs initialized by v_pk_mul (no zero-movs); xp injected post-reduce
//  * each lane activates ONLY its own gate (uniform A*sigm(m*p)+B with
//    per-lane m,A,B), then 4 DPP quad_perm broadcasts -> trans chains 5->2
//  * loop counter + branch on the scalar pipe (s20/SCC)

#define STRG(x) #x
#define WLD(R0, R3, WOFF, IMM)                                            \
    "global_load_dwordx4 v[" STRG(R0) ":" STRG(R3) "], %[" STRG(WOFF) "], %[whs] offset:" STRG(IMM) "\n\t"
#define PKQ(H0, H1, A0, A1, B0, B1, C0, C1, D0, D1)                                        \
    "v_pk_fma_f32 v[24:25], v[" STRG(A0) ":" STRG(A1) "], v[" STRG(H0) ":" STRG(H1) "], v[24:25]\n\t" \
    "v_pk_fma_f32 v[26:27], v[" STRG(B0) ":" STRG(B1) "], v[" STRG(H0) ":" STRG(H1) "], v[26:27]\n\t" \
    "v_pk_fma_f32 v[28:29], v[" STRG(C0) ":" STRG(C1) "], v[" STRG(H0) ":" STRG(H1) "], v[28:29]\n\t" \
    "v_pk_fma_f32 v[30:31], v[" STRG(D0) ":" STRG(D1) "], v[" STRG(H0) ":" STRG(H1) "], v[30:31]\n\t"
#define PKQ0(H0, H1, A0, A1, B0, B1, C0, C1, D0, D1)                                       \
    "v_pk_mul_f32 v[24:25], v[" STRG(A0) ":" STRG(A1) "], v[" STRG(H0) ":" STRG(H1) "]\n\t" \
    "v_pk_mul_f32 v[26:27], v[" STRG(B0) ":" STRG(B1) "], v[" STRG(H0) ":" STRG(H1) "]\n\t" \
    "v_pk_mul_f32 v[28:29], v[" STRG(C0) ":" STRG(C1) "], v[" STRG(H0) ":" STRG(H1) "]\n\t" \
    "v_pk_mul_f32 v[30:31], v[" STRG(D0) ":" STRG(D1) "], v[" STRG(H0) ":" STRG(H1) "]\n\t"

__global__ __launch_bounds__(512) void k_lstm(const float* __restrict__ xpf,
                                              const float* __restrict__ xpb,
                                              const float* __restrict__ whf,
                                              const float* __restrict__ whb,
                                              float* __restrict__ out) {
    const int b = blockIdx.x;
    const int dir = blockIdx.y;
    const float* __restrict__ xp = dir ? xpb : xpf;
    const float* __restrict__ wh = dir ? whb : whf;
    const int t = threadIdx.x;  // 0..511
    const int q = t >> 2;       // unit 0..127
    const int jq = t & 3;       // h-col slice [32jq, 32jq+32) == own gate type

    // Two buffers of 4 h-replicas each. Replica stride 544 B, buffer stride
    // 2176 B, total 4352 B. (R11 layout: conflict-free reads and writes.)
    __shared__ __align__(64) float h_lds[1088];
    for (int i = t; i < 1088; i += 512) h_lds[i] = 0.f;
    __syncthreads();

    unsigned hbase = (unsigned)(uintptr_t)&h_lds[0];
    unsigned rd0 = hbase + 672u * (unsigned)jq;
    unsigned rdd = rd0 ^ (rd0 + 2176u);
    unsigned wr0 = hbase + 2176u + 544u * (unsigned)jq + ((unsigned)q << 2);
    unsigned wrd = wr0 ^ (wr0 - 2176u);
    unsigned w0 = ((0u * 128u + (unsigned)q) * 128u + (unsigned)jq * 32u) * 4u;
    unsigned w1 = ((1u * 128u + (unsigned)q) * 128u + (unsigned)jq * 32u) * 4u;
    unsigned w2 = ((2u * 128u + (unsigned)q) * 128u + (unsigned)jq * 32u) * 4u;
    unsigned w3 = ((3u * 128u + (unsigned)q) * 128u + (unsigned)jq * 32u) * 4u;
    unsigned xoff = (unsigned)(b * 512 + t) * 4u + 16384u;  // prefetch = step 1
    float xp0v = xp[(size_t)b * 512 + t];
    // select masks: pick own gate's reduced sum
    float s0 = (jq == 0) ? 1.f : 0.f;
    float s1 = (jq == 1) ? 1.f : 0.f;
    float s2 = (jq == 2) ? 1.f : 0.f;
    float s3 = (jq == 3) ? 1.f : 0.f;
    // own-gate activation constants: act = A*rcp(1+2^(m*p)) + B
    // gates i,f,o (jq!=2): sigmoid -> m=-log2e, A=1, B=0
    // gate  g   (jq==2): tanh     -> m=-2log2e, A=2, B=-1
    float mlv = (jq == 2) ? -2.8853900817779268f : -1.4426950408889634f;
    float Aav = (jq == 2) ? 2.f : 1.f;
    float Bav = (jq == 2) ? -1.f : 0.f;
    float h_out;

    asm volatile(
        // ---- prologue: state init + 32x W dwordx4 loads (once) ----
        "v_mov_b32 v16, 0\n\t"        // c
        "s_movk_i32 s20, 0x800\n\t"   // counter = 2048 (scalar pipe)
        "v_mov_b32 v19, %[x0]\n\t"    // xp current
        "v_mov_b32 v21, %[xo]\n\t"    // xp prefetch offset
        "v_mov_b32 v22, %[rdb]\n\t"   // ds read base
        "v_mov_b32 v23, %[wrb]\n\t"   // ds write addr
        WLD(64, 67, w0, 0) WLD(68, 71, w0, 16) WLD(72, 75, w0, 32) WLD(76, 79, w0, 48)
        WLD(80, 83, w0, 64) WLD(84, 87, w0, 80) WLD(88, 91, w0, 96) WLD(92, 95, w0, 112)
        WLD(96, 99, w1, 0) WLD(100, 103, w1, 16) WLD(104, 107, w1, 32) WLD(108, 111, w1, 48)
        WLD(112, 115, w1, 64) WLD(116, 119, w1, 80) WLD(120, 123, w1, 96) WLD(124, 127, w1, 112)
        WLD(128, 131, w2, 0) WLD(132, 135, w2, 16) WLD(136, 139, w2, 32) WLD(140, 143, w2, 48)
        WLD(144, 147, w2, 64) WLD(148, 151, w2, 80) WLD(152, 155, w2, 96) WLD(156, 159, w2, 112)
        WLD(160, 163, w3, 0) WLD(164, 167, w3, 16) WLD(168, 171, w3, 32) WLD(172, 175, w3, 48)
        WLD(176, 179, w3, 64) WLD(180, 183, w3, 80) WLD(184, 187, w3, 96) WLD(188, 191, w3, 112)
        "s_waitcnt vmcnt(0)\n\t"
        // ---- main loop ----
        "LSTM_TOP%=:\n\t"
        "global_load_dword v20, v21, %[xps]\n\t"  // prefetch xp step+1
        "ds_read_b128 v[32:35], v22\n\t"
        "ds_read_b128 v[36:39], v22 offset:16\n\t"
        "ds_read_b128 v[40:43], v22 offset:32\n\t"
        "ds_read_b128 v[44:47], v22 offset:48\n\t"
        "ds_read_b128 v[48:51], v22 offset:64\n\t"
        "ds_read_b128 v[52:55], v22 offset:80\n\t"
        "ds_read_b128 v[56:59], v22 offset:96\n\t"
        "ds_read_b128 v[60:63], v22 offset:112\n\t"
        "v_xor_b32 v22, %[rdd], v22\n\t"  // early: toggle read buffer
        "v_add_u32 v21, 0x4000, v21\n\t"  // early: advance xp offset
        // 64 packed FMAs, chunked: start chunk k when its ds_read has landed
        "s_waitcnt lgkmcnt(7)\n\t"
        PKQ0(32, 33, 64, 65, 96, 97, 128, 129, 160, 161)
        PKQ(34, 35, 66, 67, 98, 99, 130, 131, 162, 163)
        "s_waitcnt lgkmcnt(6)\n\t"
        PKQ(36, 37, 68, 69, 100, 101, 132, 133, 164, 165)
        PKQ(38, 39, 70, 71, 102, 103, 134, 135, 166, 167)
        "s_waitcnt lgkmcnt(5)\n\t"
        PKQ(40, 41, 72, 73, 104, 105, 136, 137, 168, 169)
        PKQ(42, 43, 74, 75, 106, 107, 138, 139, 170, 171)
        "s_waitcnt lgkmcnt(4)\n\t"
        PKQ(44, 45, 76, 77, 108, 109, 140, 141, 172, 173)
        PKQ(46, 47, 78, 79, 110, 111, 142, 143, 174, 175)
        "s_waitcnt lgkmcnt(3)\n\t"
        PKQ(48, 49, 80, 81, 112, 113, 144, 145, 176, 177)
        PKQ(50, 51, 82, 83, 114, 115, 146, 147, 178, 179)
        "s_waitcnt lgkmcnt(2)\n\t"
        PKQ(52, 53, 84, 85, 116, 117, 148, 149, 180, 181)
        PKQ(54, 55, 86, 87, 118, 119, 150, 151, 182, 183)
        "s_waitcnt lgkmcnt(1)\n\t"
        PKQ(56, 57, 88, 89, 120, 121, 152, 153, 184, 185)
        PKQ(58, 59, 90, 91, 122, 123, 154, 155, 186, 187)
        "s_waitcnt lgkmcnt(0)\n\t"
        PKQ(60, 61, 92, 93, 124, 125, 156, 157, 188, 189)
        PKQ(62, 63, 94, 95, 126, 127, 158, 159, 190, 191)
        // horizontal add of packed halves
        "v_add_f32 v8, v24, v25\n\t"
        "v_add_f32 v9, v26, v27\n\t"
        "v_add_f32 v10, v28, v29\n\t"
        "v_add_f32 v11, v30, v31\n\t"
        // quad reduction via DPP butterflies (no LDS, no waits)
        "v_mov_b32_dpp v12, v8 quad_perm:[1,0,3,2] row_mask:0xf bank_mask:0xf\n\t"
        "v_mov_b32_dpp v13, v9 quad_perm:[1,0,3,2] row_mask:0xf bank_mask:0xf\n\t"
        "v_mov_b32_dpp v14, v10 quad_perm:[1,0,3,2] row_mask:0xf bank_mask:0xf\n\t"
        "v_mov_b32_dpp v15, v11 quad_perm:[1,0,3,2] row_mask:0xf bank_mask:0xf\n\t"
        "v_add_f32 v8, v8, v12\n\t"
        "v_add_f32 v9, v9, v13\n\t"
        "v_add_f32 v10, v10, v14\n\t"
        "v_add_f32 v11, v11, v15\n\t"
        "v_mov_b32_dpp v12, v8 quad_perm:[2,3,0,1] row_mask:0xf bank_mask:0xf\n\t"
        "v_mov_b32_dpp v13, v9 quad_perm:[2,3,0,1] row_mask:0xf bank_mask:0xf\n\t"
        "v_mov_b32_dpp v14, v10 quad_perm:[2,3,0,1] row_mask:0xf bank_mask:0xf\n\t"
        "v_mov_b32_dpp v15, v11 quad_perm:[2,3,0,1] row_mask:0xf bank_mask:0xf\n\t"
        "v_add_f32 v8, v8, v12\n\t"
        "v_add_f32 v9, v9, v13\n\t"
        "v_add_f32 v10, v10, v14\n\t"
        "v_add_f32 v11, v11, v15\n\t"
        // select own gate's sum, inject xp
        "v_mul_f32 v12, %[s0], v8\n\t"
        "v_fma_f32 v12, %[s1], v9, v12\n\t"
        "v_fma_f32 v12, %[s2], v10, v12\n\t"
        "v_fma_f32 v12, %[s3], v11, v12\n\t"
        "v_add_f32 v12, v12, v19\n\t"
        // own-gate activation: act = A*rcp(1+2^(m*p)) + B   (2 trans total)
        "v_mul_f32 v13, %[ml], v12\n\t"
        "v_exp_f32 v13, v13\n\t"
        "s_nop 1\n\t"
        "v_add_f32 v13, 1.0, v13\n\t"
        "v_rcp_f32 v13, v13\n\t"
        "s_nop 1\n\t"
        "v_fma_f32 v12, %[Aa], v13, %[Ba]\n\t"  // act(own gate) in v12
        "s_nop 1\n\t"
        // broadcast the 4 activated gates across the quad
        "v_mov_b32_dpp v13, v12 quad_perm:[0,0,0,0] row_mask:0xf bank_mask:0xf\n\t"  // sig(i)
        "v_mov_b32_dpp v14, v12 quad_perm:[2,2,2,2] row_mask:0xf bank_mask:0xf\n\t"  // tanh(g)
        "v_mov_b32_dpp v15, v12 quad_perm:[1,1,1,1] row_mask:0xf bank_mask:0xf\n\t"  // sig(f)
        "v_mov_b32_dpp v17, v12 quad_perm:[3,3,3,3] row_mask:0xf bank_mask:0xf\n\t"  // sig(o)
        "v_mul_f32 v13, v13, v14\n\t"       // i*g (gaps 4,3 from dpp writes)
        "v_fma_f32 v16, v15, v16, v13\n\t"  // c = f*c + i*g (v15 gap 3)
        // tanh(c) chain
        "v_mul_f32 v14, 0xc038aa3b, v16\n\t"
        "v_exp_f32 v14, v14\n\t"
        "s_nop 1\n\t"
        "v_add_f32 v14, 1.0, v14\n\t"
        "v_rcp_f32 v14, v14\n\t"
        "s_nop 1\n\t"
        "v_fma_f32 v14, 2.0, v14, -1.0\n\t"  // tanh(c)
        "v_mul_f32 v17, v14, v17\n\t"        // h = tanh(c)*sig(o)
        // publish h: lane jq writes replica jq
        "ds_write_b32 v23, v17\n\t"
        "s_waitcnt vmcnt(0) lgkmcnt(0)\n\t"
        "v_mov_b32 v19, v20\n\t"  // xpCur = prefetched
        "s_barrier\n\t"
        "v_xor_b32 v23, %[wrd], v23\n\t"  // toggle write buffer
        "s_sub_u32 s20, s20, 1\n\t"
        "s_cmp_lg_u32 s20, 0\n\t"
        "s_cbranch_scc1 LSTM_TOP%=\n\t"
        "v_mov_b32 %[ho], v17\n\t"
        : [ho] "=v"(h_out)
        : [w0] "v"(w0), [w1] "v"(w1), [w2] "v"(w2), [w3] "v"(w3),
          [whs] "s"(wh), [xps] "s"(xp),
          [xo] "v"(xoff), [rdb] "v"(rd0), [wrb] "v"(wr0),
          [rdd] "v"(rdd), [wrd] "v"(wrd), [x0] "v"(xp0v),
          [s0] "v"(s0), [s1] "v"(s1), [s2] "v"(s2), [s3] "v"(s3),
          [ml] "v"(mlv), [Aa] "v"(Aav), [Ba] "v"(Bav)
        : "memory", "vcc", "scc", "s20",
          "v8", "v9", "v10", "v11", "v12", "v13", "v14", "v15", "v16", "v17",
          "v18", "v19", "v20", "v21", "v22", "v23", "v24", "v25", "v26", "v27",
          "v28", "v29", "v30", "v31", "v32", "v33", "v34", "v35", "v36", "v37",
          "v38", "v39", "v40", "v41", "v42", "v43", "v44", "v45", "v46", "v47",
          "v48", "v49", "v50", "v51", "v52", "v53", "v54", "v55", "v56", "v57",
          "v58", "v59", "v60", "v61", "v62", "v63", "v64", "v65", "v66", "v67",
          "v68", "v69", "v70", "v71", "v72", "v73", "v74", "v75", "v76", "v77",
          "v78", "v79", "v80", "v81", "v82", "v83", "v84", "v85", "v86", "v87",
          "v88", "v89", "v90", "v91", "v92", "v93", "v94", "v95", "v96", "v97",
          "v98", "v99", "v100", "v101", "v102", "v103", "v104", "v105", "v106", "v107",
          "v108", "v109", "v110", "v111", "v112", "v113", "v114", "v115", "v116", "v117",
          "v118", "v119", "v120", "v121", "v122", "v123", "v124", "v125", "v126", "v127",
          "v128", "v129", "v130", "v131", "v132", "v133", "v134", "v135", "v136", "v137",
          "v138", "v139", "v140", "v141", "v142", "v143", "v144", "v145", "v146", "v147",
          "v148", "v149", "v150", "v151", "v152", "v153", "v154", "v155", "v156", "v157",
          "v158", "v159", "v160", "v161", "v162", "v163", "v164", "v165", "v166", "v167",
          "v168", "v169", "v170", "v171", "v172", "v173", "v174", "v175", "v176", "v177",
          "v178", "v179", "v180", "v181", "v182", "v183", "v184", "v185", "v186", "v187",
          "v188", "v189", "v190", "v191");

    if (jq == 0) out[(size_t)b * 256 + dir * HH + q] = h_out;
}

extern "C" void kernel_launch(void* const* d_in, const int* in_sizes, int n_in,
                              void* d_out, int out_size, void* d_ws, size_t ws_size,
                              hipStream_t stream) {
    const float* x = (const float*)d_in[0];
    const int* adj = (const int*)d_in[1];
    const float* wif = (const float*)d_in[2];
    const float* whf = (const float*)d_in[3];
    const float* bif = (const float*)d_in[4];
    const float* bhf = (const float*)d_in[5];
    const float* wib = (const float*)d_in[6];
    const float* whb = (const float*)d_in[7];
    const float* bib = (const float*)d_in[8];
    const float* bhb = (const float*)d_in[9];
    float* out = (float*)d_out;

    // Layout: xpf | xpb | xa  (so the last-iteration xp prefetch overrun
    // lands in mapped scratch).
    float* xpf = (float*)d_ws;                 // [N][B][512]
    float* xpb = xpf + (size_t)NN * BB * 512;  // [N][B][512]
    float* xa = xpb + (size_t)NN * BB * 512;   // [B][N][D]

    k_agg<<<dim3(NN / TI, BB), 256, 0, stream>>>(x, adj, xa);
    k_proj<<<dim3((NN * BB) / MT, 1024 / GT), 256, 0, stream>>>(xa, wif, wib, bif, bhf, bib, bhb,
                                                                xpf, xpb);
    k_lstm<<<dim3(BB, 2), 512, 0, stream>>>(xpf, xpb, whf, whb, out);
}

// Round 13
// 1246.742 us; speedup vs baseline: 47.3453x; 1.0933x over previous
//
#include <hip/hip_runtime.h>
#include <math.h>

#define BB 8
#define NN 2048
#define DD 128
#define HH 128

typedef float f4 __attribute__((ext_vector_type(4)));
typedef __attribute__((ext_vector_type(8))) short s16x8;
typedef __attribute__((ext_vector_type(8))) unsigned short u16x8;

__device__ __forceinline__ float fast_rcp(float x) { return __builtin_amdgcn_rcpf(x); }

// round-to-nearest-even bf16 split: x ~= hi + lo (each exactly bf16)
__device__ __forceinline__ void bsplit(float x, unsigned short& h, unsigned short& l) {
    unsigned u = __float_as_uint(x);
    unsigned r = u + 0x7FFFu + ((u >> 16) & 1u);
    h = (unsigned short)(r >> 16);
    float xh = __uint_as_float(((unsigned)h) << 16);
    float d = x - xh;
    unsigned u2 = __float_as_uint(d);
    unsigned r2 = u2 + 0x7FFFu + ((u2 >> 16) & 1u);
    l = (unsigned short)(r2 >> 16);
}

// ---------------- Kernel 0: transpose + bf16-split x ----------------
// x[b][n][d] fp32 -> xTh/xTl[b][d][n] bf16 (hi/lo Dekker split).
__global__ __launch_bounds__(256) void k_xT(const float* __restrict__ x,
                                            unsigned short* __restrict__ xth,
                                            unsigned short* __restrict__ xtl) {
    __shared__ __align__(16) unsigned short th[32][72];
    __shared__ __align__(16) unsigned short tl[32][72];
    const int n0 = blockIdx.x * 64;
    const int d0 = blockIdx.y * 32;
    const int b = blockIdx.z;
    const int tid = threadIdx.x;
    {
        const int nl = tid & 63, dseg = tid >> 6;  // dseg 0..3 -> 8 d each
        const float* xp = x + ((size_t)b * NN + n0 + nl) * DD + d0 + dseg * 8;
        float4 v0 = *(const float4*)(xp);
        float4 v1 = *(const float4*)(xp + 4);
        const float* vv = (const float*)&v0;
#pragma unroll
        for (int j = 0; j < 4; ++j) {
            unsigned short hh, ll;
            bsplit(vv[j], hh, ll);
            th[dseg * 8 + j][nl] = hh;
            tl[dseg * 8 + j][nl] = ll;
        }
        const float* vw = (const float*)&v1;
#pragma unroll
        for (int j = 0; j < 4; ++j) {
            unsigned short hh, ll;
            bsplit(vw[j], hh, ll);
            th[dseg * 8 + 4 + j][nl] = hh;
            tl[dseg * 8 + 4 + j][nl] = ll;
        }
    }
    __syncthreads();
    {
        const int dl = tid >> 3, nseg = tid & 7;  // 32 d x 8 nsegs of 8
        u16x8 vh = *(const u16x8*)&th[dl][nseg * 8];
        u16x8 vl = *(const u16x8*)&tl[dl][nseg * 8];
        size_t off = ((size_t)b * DD + d0 + dl) * NN + n0 + nseg * 8;
        *(u16x8*)(xth + off) = vh;
        *(u16x8*)(xtl + off) = vl;
    }
}

// ---------------- Kernel 1: graph aggregation via MFMA ----------------
// xa[b][i][d] = (Sum_k A'[i][k] * x[k][d]) / (Sum_k A'[i][k]),  A' = I + (adj>0)
// (numerator includes x_i via the I term; ones-B MFMA gives 1+deg exactly)
// A-frag: row=lane&15, k=8*(lane>>4)+j (contiguous). C/D: col=lane&15,
// row=4*(lane>>4)+reg (m89-verified). x via hi/lo bf16 split, fp32 accum.
__global__ __launch_bounds__(256) void k_agg2(const int* __restrict__ adj,
                                              const unsigned short* __restrict__ xth,
                                              const unsigned short* __restrict__ xtl,
                                              float* __restrict__ xa) {
    __shared__ __align__(16) unsigned short Al[64][40];
    __shared__ __align__(16) unsigned short Xh[128][40];
    __shared__ __align__(16) unsigned short Xl[128][40];
    const int b = blockIdx.y;
    const int i0 = blockIdx.x * 64;
    const int tid = threadIdx.x;
    const int wave = tid >> 6, lane = tid & 63;
    const int ar = tid >> 2, aks = (tid & 3) * 8;   // adj staging: row, k-octet
    const int xd = tid >> 1, xks = (tid & 1) * 16;  // xT staging: d, k-16seg
    const int* ap = adj + ((size_t)b * NN + i0 + ar) * NN + aks;
    const unsigned short* hp = xth + ((size_t)b * DD + xd) * NN + xks;
    const unsigned short* lp = xtl + ((size_t)b * DD + xd) * NN + xks;

    f4 acc[8], dacc;
#pragma unroll
    for (int t = 0; t < 8; ++t) acc[t] = {0.f, 0.f, 0.f, 0.f};
    dacc = {0.f, 0.f, 0.f, 0.f};
    const short onebf = (short)0x3F80;
    s16x8 ones = {onebf, onebf, onebf, onebf, onebf, onebf, onebf, onebf};

    int4 a0 = *(const int4*)(ap);
    int4 a1 = *(const int4*)(ap + 4);
    u16x8 h0 = *(const u16x8*)(hp);
    u16x8 h1 = *(const u16x8*)(hp + 8);
    u16x8 l0 = *(const u16x8*)(lp);
    u16x8 l1 = *(const u16x8*)(lp + 8);

    for (int k0 = 0; k0 < NN; k0 += 32) {
        {
            u16x8 w;
            const int* av0 = (const int*)&a0;
            const int* av1 = (const int*)&a1;
            int colb = k0 + aks, myrow = i0 + ar;
#pragma unroll
            for (int j = 0; j < 4; ++j) {
                int c0 = (av0[j] > 0 ? 1 : 0) + (myrow == colb + j ? 1 : 0);
                int c1 = (av1[j] > 0 ? 1 : 0) + (myrow == colb + 4 + j ? 1 : 0);
                w[j] = c0 == 0 ? 0 : (c0 == 1 ? 0x3F80 : 0x4000);
                w[4 + j] = c1 == 0 ? 0 : (c1 == 1 ? 0x3F80 : 0x4000);
            }
            *(u16x8*)&Al[ar][aks] = w;
            *(u16x8*)&Xh[xd][xks] = h0;
            *(u16x8*)&Xh[xd][xks + 8] = h1;
            *(u16x8*)&Xl[xd][xks] = l0;
            *(u16x8*)&Xl[xd][xks + 8] = l1;
        }
        __syncthreads();
        if (k0 + 32 < NN) {  // prefetch next tile into regs (overlaps compute)
            a0 = *(const int4*)(ap + k0 + 32);
            a1 = *(const int4*)(ap + k0 + 36);
            h0 = *(const u16x8*)(hp + k0 + 32);
            h1 = *(const u16x8*)(hp + k0 + 40);
            l0 = *(const u16x8*)(lp + k0 + 32);
            l1 = *(const u16x8*)(lp + k0 + 40);
        }
        s16x8 afr = *(const s16x8*)&Al[16 * wave + (lane & 15)][(lane >> 4) * 8];
#pragma unroll
        for (int t = 0; t < 8; ++t) {
            s16x8 bh = *(const s16x8*)&Xh[16 * t + (lane & 15)][(lane >> 4) * 8];
            s16x8 bl = *(const s16x8*)&Xl[16 * t + (lane & 15)][(lane >> 4) * 8];
            acc[t] = __builtin_amdgcn_mfma_f32_16x16x32_bf16(afr, bh, acc[t], 0, 0, 0);
            acc[t] = __builtin_amdgcn_mfma_f32_16x16x32_bf16(afr, bl, acc[t], 0, 0, 0);
        }
        dacc = __builtin_amdgcn_mfma_f32_16x16x32_bf16(afr, ones, dacc, 0, 0, 0);
        __syncthreads();
    }
    float inv[4];
#pragma unroll
    for (int r = 0; r < 4; ++r) inv[r] = fast_rcp(dacc[r]);
#pragma unroll
    for (int t = 0; t < 8; ++t)
#pragma unroll
        for (int r = 0; r < 4; ++r) {
            int row = i0 + 16 * wave + (lane >> 4) * 4 + r;
            xa[((size_t)b * NN + row) * DD + 16 * t + (lane & 15)] = acc[t][r] * inv[r];
        }
}

// ---------------- Kernel 2: input projection (both dirs) ----------------
#define MT 64
#define GT 32

__global__ __launch_bounds__(256) void k_proj(const float* __restrict__ xa,
                                              const float* __restrict__ wif,
                                              const float* __restrict__ wib,
                                              const float* __restrict__ bif,
                                              const float* __restrict__ bhf,
                                              const float* __restrict__ bib,
                                              const float* __restrict__ bhb,
                                              float* __restrict__ xpf,
                                              float* __restrict__ xpb) {
    __shared__ __align__(16) float xs[MT][132];
    __shared__ __align__(16) float wl[GT][132];
    const int r0 = blockIdx.x * MT;
    const int g0 = blockIdx.y * GT;
    const int tid = threadIdx.x;
#pragma unroll
    for (int k = 0; k < 8; ++k) {
        int idx = tid + k * 256;
        int row = idx >> 5, c4 = idx & 31;
        int r = r0 + row;
        int t = r >> 3, bb = r & 7;
        float4 v = *(const float4*)(xa + ((size_t)bb * NN + t) * DD + c4 * 4);
        *(float4*)(&xs[row][c4 * 4]) = v;
    }
#pragma unroll
    for (int k = 0; k < 4; ++k) {
        int idx = tid + k * 256;
        int row = idx >> 5, c4 = idx & 31;
        int g = g0 + row;
        const float* wsrc = (g < 512) ? (wif + (size_t)g * DD) : (wib + (size_t)(g - 512) * DD);
        *(float4*)(&wl[row][c4 * 4]) = *(const float4*)(wsrc + c4 * 4);
    }
    __syncthreads();
    const int mg = tid >> 4;
    const int gg = tid & 15;
    float acc[4][2];
#pragma unroll
    for (int i = 0; i < 4; ++i) { acc[i][0] = 0.f; acc[i][1] = 0.f; }
#pragma unroll 8
    for (int d4 = 0; d4 < 32; ++d4) {
        float4 xv[4], wv[2];
#pragma unroll
        for (int i = 0; i < 4; ++i) xv[i] = *(const float4*)(&xs[mg * 4 + i][d4 * 4]);
        wv[0] = *(const float4*)(&wl[gg * 2 + 0][d4 * 4]);
        wv[1] = *(const float4*)(&wl[gg * 2 + 1][d4 * 4]);
#pragma unroll
        for (int i = 0; i < 4; ++i) {
#pragma unroll
            for (int j = 0; j < 2; ++j) {
                acc[i][j] = fmaf(xv[i].x, wv[j].x, acc[i][j]);
                acc[i][j] = fmaf(xv[i].y, wv[j].y, acc[i][j]);
                acc[i][j] = fmaf(xv[i].z, wv[j].z, acc[i][j]);
                acc[i][j] = fmaf(xv[i].w, wv[j].w, acc[i][j]);
            }
        }
    }
#pragma unroll
    for (int j = 0; j < 2; ++j) {
        int g = g0 + gg * 2 + j;
        float bias = (g < 512) ? (bif[g] + bhf[g]) : (bib[g - 512] + bhb[g - 512]);
#pragma unroll
        for (int i = 0; i < 4; ++i) {
            int r = r0 + mg * 4 + i;
            int t = r >> 3, bb = r & 7;
            float v = acc[i][j] + bias;
            if (g < 512) {
                int p = 4 * (g & 127) + (g >> 7);
                xpf[((size_t)t * BB + bb) * 512 + p] = v;
            } else {
                int gb = g - 512;
                int p = 4 * (gb & 127) + (gb >> 7);
                xpb[((size_t)(NN - 1 - t) * BB + bb) * 512 + p] = v;
            }
        }
    }
}

// ---------------- Kernel 3: LSTM recurrence (full inline-asm loop) ---------
// (R11/R12 structure: replica-padded LDS, DPP reduce, own-gate activation,
//  chunked lgkm waits, scalar loop counter. R13: lgkm/vmcnt wait split so the
//  xp-prefetch wait overlaps barrier arrival.)

#define STRG(x) #x
#define WLD(R0, R3, WOFF, IMM)                                            \
    "global_load_dwordx4 v[" STRG(R0) ":" STRG(R3) "], %[" STRG(WOFF) "], %[whs] offset:" STRG(IMM) "\n\t"
#define PKQ(H0, H1, A0, A1, B0, B1, C0, C1, D0, D1)                                        \
    "v_pk_fma_f32 v[24:25], v[" STRG(A0) ":" STRG(A1) "], v[" STRG(H0) ":" STRG(H1) "], v[24:25]\n\t" \
    "v_pk_fma_f32 v[26:27], v[" STRG(B0) ":" STRG(B1) "], v[" STRG(H0) ":" STRG(H1) "], v[26:27]\n\t" \
    "v_pk_fma_f32 v[28:29], v[" STRG(C0) ":" STRG(C1) "], v[" STRG(H0) ":" STRG(H1) "], v[28:29]\n\t" \
    "v_pk_fma_f32 v[30:31], v[" STRG(D0) ":" STRG(D1) "], v[" STRG(H0) ":" STRG(H1) "], v[30:31]\n\t"
#define PKQ0(H0, H1, A0, A1, B0, B1, C0, C1, D0, D1)                                       \
    "v_pk_mul_f32 v[24:25], v[" STRG(A0) ":" STRG(A1) "], v[" STRG(H0) ":" STRG(H1) "]\n\t" \
    "v_pk_mul_f32 v[26:27], v[" STRG(B0) ":" STRG(B1) "], v[" STRG(H0) ":" STRG(H1) "]\n\t" \
    "v_pk_mul_f32 v[28:29], v[" STRG(C0) ":" STRG(C1) "], v[" STRG(H0) ":" STRG(H1) "]\n\t" \
    "v_pk_mul_f32 v[30:31], v[" STRG(D0) ":" STRG(D1) "], v[" STRG(H0) ":" STRG(H1) "]\n\t"

__global__ __launch_bounds__(512) void k_lstm(const float* __restrict__ xpf,
                                              const float* __restrict__ xpb,
                                              const float* __restrict__ whf,
                                              const float* __restrict__ whb,
                                              float* __restrict__ out) {
    const int b = blockIdx.x;
    const int dir = blockIdx.y;
    const float* __restrict__ xp = dir ? xpb : xpf;
    const float* __restrict__ wh = dir ? whb : whf;
    const int t = threadIdx.x;  // 0..511
    const int q = t >> 2;       // unit 0..127
    const int jq = t & 3;       // h-col slice / own gate type

    __shared__ __align__(64) float h_lds[1088];
    for (int i = t; i < 1088; i += 512) h_lds[i] = 0.f;
    __syncthreads();

    unsigned hbase = (unsigned)(uintptr_t)&h_lds[0];
    unsigned rd0 = hbase + 672u * (unsigned)jq;
    unsigned rdd = rd0 ^ (rd0 + 2176u);
    unsigned wr0 = hbase + 2176u + 544u * (unsigned)jq + ((unsigned)q << 2);
    unsigned wrd = wr0 ^ (wr0 - 2176u);
    unsigned w0 = ((0u * 128u + (unsigned)q) * 128u + (unsigned)jq * 32u) * 4u;
    unsigned w1 = ((1u * 128u + (unsigned)q) * 128u + (unsigned)jq * 32u) * 4u;
    unsigned w2 = ((2u * 128u + (unsigned)q) * 128u + (unsigned)jq * 32u) * 4u;
    unsigned w3 = ((3u * 128u + (unsigned)q) * 128u + (unsigned)jq * 32u) * 4u;
    unsigned xoff = (unsigned)(b * 512 + t) * 4u + 16384u;  // prefetch = step 1
    float xp0v = xp[(size_t)b * 512 + t];
    float s0 = (jq == 0) ? 1.f : 0.f;
    float s1 = (jq == 1) ? 1.f : 0.f;
    float s2 = (jq == 2) ? 1.f : 0.f;
    float s3 = (jq == 3) ? 1.f : 0.f;
    float mlv = (jq == 2) ? -2.8853900817779268f : -1.4426950408889634f;
    float Aav = (jq == 2) ? 2.f : 1.f;
    float Bav = (jq == 2) ? -1.f : 0.f;
    float h_out;

    asm volatile(
        "v_mov_b32 v16, 0\n\t"        // c
        "s_movk_i32 s20, 0x800\n\t"   // counter = 2048
        "v_mov_b32 v19, %[x0]\n\t"
        "v_mov_b32 v21, %[xo]\n\t"
        "v_mov_b32 v22, %[rdb]\n\t"
        "v_mov_b32 v23, %[wrb]\n\t"
        WLD(64, 67, w0, 0) WLD(68, 71, w0, 16) WLD(72, 75, w0, 32) WLD(76, 79, w0, 48)
        WLD(80, 83, w0, 64) WLD(84, 87, w0, 80) WLD(88, 91, w0, 96) WLD(92, 95, w0, 112)
        WLD(96, 99, w1, 0) WLD(100, 103, w1, 16) WLD(104, 107, w1, 32) WLD(108, 111, w1, 48)
        WLD(112, 115, w1, 64) WLD(116, 119, w1, 80) WLD(120, 123, w1, 96) WLD(124, 127, w1, 112)
        WLD(128, 131, w2, 0) WLD(132, 135, w2, 16) WLD(136, 139, w2, 32) WLD(140, 143, w2, 48)
        WLD(144, 147, w2, 64) WLD(148, 151, w2, 80) WLD(152, 155, w2, 96) WLD(156, 159, w2, 112)
        WLD(160, 163, w3, 0) WLD(164, 167, w3, 16) WLD(168, 171, w3, 32) WLD(172, 175, w3, 48)
        WLD(176, 179, w3, 64) WLD(180, 183, w3, 80) WLD(184, 187, w3, 96) WLD(188, 191, w3, 112)
        "s_waitcnt vmcnt(0)\n\t"
        "LSTM_TOP%=:\n\t"
        "global_load_dword v20, v21, %[xps]\n\t"
        "ds_read_b128 v[32:35], v22\n\t"
        "ds_read_b128 v[36:39], v22 offset:16\n\t"
        "ds_read_b128 v[40:43], v22 offset:32\n\t"
        "ds_read_b128 v[44:47], v22 offset:48\n\t"
        "ds_read_b128 v[48:51], v22 offset:64\n\t"
        "ds_read_b128 v[52:55], v22 offset:80\n\t"
        "ds_read_b128 v[56:59], v22 offset:96\n\t"
        "ds_read_b128 v[60:63], v22 offset:112\n\t"
        "v_xor_b32 v22, %[rdd], v22\n\t"
        "v_add_u32 v21, 0x4000, v21\n\t"
        "s_waitcnt lgkmcnt(7)\n\t"
        PKQ0(32, 33, 64, 65, 96, 97, 128, 129, 160, 161)
        PKQ(34, 35, 66, 67, 98, 99, 130, 131, 162, 163)
        "s_waitcnt lgkmcnt(6)\n\t"
        PKQ(36, 37, 68, 69, 100, 101, 132, 133, 164, 165)
        PKQ(38, 39, 70, 71, 102, 103, 134, 135, 166, 167)
        "s_waitcnt lgkmcnt(5)\n\t"
        PKQ(40, 41, 72, 73, 104, 105, 136, 137, 168, 169)
        PKQ(42, 43, 74, 75, 106, 107, 138, 139, 170, 171)
        "s_waitcnt lgkmcnt(4)\n\t"
        PKQ(44, 45, 76, 77, 108, 109, 140, 141, 172, 173)
        PKQ(46, 47, 78, 79, 110, 111, 142, 143, 174, 175)
        "s_waitcnt lgkmcnt(3)\n\t"
        PKQ(48, 49, 80, 81, 112, 113, 144, 145, 176, 177)
        PKQ(50, 51, 82, 83, 114, 115, 146, 147, 178, 179)
        "s_waitcnt lgkmcnt(2)\n\t"
        PKQ(52, 53, 84, 85, 116, 117, 148, 149, 180, 181)
        PKQ(54, 55, 86, 87, 118, 119, 150, 151, 182, 183)
        "s_waitcnt lgkmcnt(1)\n\t"
        PKQ(56, 57, 88, 89, 120, 121, 152, 153, 184, 185)
        PKQ(58, 59, 90, 91, 122, 123, 154, 155, 186, 187)
        "s_waitcnt lgkmcnt(0)\n\t"
        PKQ(60, 61, 92, 93, 124, 125, 156, 157, 188, 189)
        PKQ(62, 63, 94, 95, 126, 127, 158, 159, 190, 191)
        "v_add_f32 v8, v24, v25\n\t"
        "v_add_f32 v9, v26, v27\n\t"
        "v_add_f32 v10, v28, v29\n\t"
        "v_add_f32 v11, v30, v31\n\t"
        "v_mov_b32_dpp v12, v8 quad_perm:[1,0,3,2] row_mask:0xf bank_mask:0xf\n\t"
        "v_mov_b32_dpp v13, v9 quad_perm:[1,0,3,2] row_mask:0xf bank_mask:0xf\n\t"
        "v_mov_b32_dpp v14, v10 quad_perm:[1,0,3,2] row_mask:0xf bank_mask:0xf\n\t"
        "v_mov_b32_dpp v15, v11 quad_perm:[1,0,3,2] row_mask:0xf bank_mask:0xf\n\t"
        "v_add_f32 v8, v8, v12\n\t"
        "v_add_f32 v9, v9, v13\n\t"
        "v_add_f32 v10, v10, v14\n\t"
        "v_add_f32 v11, v11, v15\n\t"
        "v_mov_b32_dpp v12, v8 quad_perm:[2,3,0,1] row_mask:0xf bank_mask:0xf\n\t"
        "v_mov_b32_dpp v13, v9 quad_perm:[2,3,0,1] row_mask:0xf bank_mask:0xf\n\t"
        "v_mov_b32_dpp v14, v10 quad_perm:[2,3,0,1] row_mask:0xf bank_mask:0xf\n\t"
        "v_mov_b32_dpp v15, v11 quad_perm:[2,3,0,1] row_mask:0xf bank_mask:0xf\n\t"
        "v_add_f32 v8, v8, v12\n\t"
        "v_add_f32 v9, v9, v13\n\t"
        "v_add_f32 v10, v10, v14\n\t"
        "v_add_f32 v11, v11, v15\n\t"
        "v_mul_f32 v12, %[s0], v8\n\t"
        "v_fma_f32 v12, %[s1], v9, v12\n\t"
        "v_fma_f32 v12, %[s2], v10, v12\n\t"
        "v_fma_f32 v12, %[s3], v11, v12\n\t"
        "v_add_f32 v12, v12, v19\n\t"
        "v_mul_f32 v13, %[ml], v12\n\t"
        "v_exp_f32 v13, v13\n\t"
        "s_nop 1\n\t"
        "v_add_f32 v13, 1.0, v13\n\t"
        "v_rcp_f32 v13, v13\n\t"
        "s_nop 1\n\t"
        "v_fma_f32 v12, %[Aa], v13, %[Ba]\n\t"
        "s_nop 1\n\t"
        "v_mov_b32_dpp v13, v12 quad_perm:[0,0,0,0] row_mask:0xf bank_mask:0xf\n\t"
        "v_mov_b32_dpp v14, v12 quad_perm:[2,2,2,2] row_mask:0xf bank_mask:0xf\n\t"
        "v_mov_b32_dpp v15, v12 quad_perm:[1,1,1,1] row_mask:0xf bank_mask:0xf\n\t"
        "v_mov_b32_dpp v17, v12 quad_perm:[3,3,3,3] row_mask:0xf bank_mask:0xf\n\t"
        "v_mul_f32 v13, v13, v14\n\t"
        "v_fma_f32 v16, v15, v16, v13\n\t"
        "v_mul_f32 v14, 0xc038aa3b, v16\n\t"
        "v_exp_f32 v14, v14\n\t"
        "s_nop 1\n\t"
        "v_add_f32 v14, 1.0, v14\n\t"
        "v_rcp_f32 v14, v14\n\t"
        "s_nop 1\n\t"
        "v_fma_f32 v14, 2.0, v14, -1.0\n\t"
        "v_mul_f32 v17, v14, v17\n\t"
        "ds_write_b32 v23, v17\n\t"
        "s_waitcnt lgkmcnt(0)\n\t"
        "s_barrier\n\t"
        "s_waitcnt vmcnt(0)\n\t"
        "v_mov_b32 v19, v20\n\t"
        "v_xor_b32 v23, %[wrd], v23\n\t"
        "s_sub_u32 s20, s20, 1\n\t"
        "s_cmp_lg_u32 s20, 0\n\t"
        "s_cbranch_scc1 LSTM_TOP%=\n\t"
        "v_mov_b32 %[ho], v17\n\t"
        : [ho] "=v"(h_out)
        : [w0] "v"(w0), [w1] "v"(w1), [w2] "v"(w2), [w3] "v"(w3),
          [whs] "s"(wh), [xps] "s"(xp),
          [xo] "v"(xoff), [rdb] "v"(rd0), [wrb] "v"(wr0),
          [rdd] "v"(rdd), [wrd] "v"(wrd), [x0] "v"(xp0v),
          [s0] "v"(s0), [s1] "v"(s1), [s2] "v"(s2), [s3] "v"(s3),
          [ml] "v"(mlv), [Aa] "v"(Aav), [Ba] "v"(Bav)
        : "memory", "vcc", "scc", "s20",
          "v8", "v9", "v10", "v11", "v12", "v13", "v14", "v15", "v16", "v17",
          "v18", "v19", "v20", "v21", "v22", "v23", "v24", "v25", "v26", "v27",
          "v28", "v29", "v30", "v31", "v32", "v33", "v34", "v35", "v36", "v37",
          "v38", "v39", "v40", "v41", "v42", "v43", "v44", "v45", "v46", "v47",
          "v48", "v49", "v50", "v51", "v52", "v53", "v54", "v55", "v56", "v57",
          "v58", "v59", "v60", "v61", "v62", "v63", "v64", "v65", "v66", "v67",
          "v68", "v69", "v70", "v71", "v72", "v73", "v74", "v75", "v76", "v77",
          "v78", "v79", "v80", "v81", "v82", "v83", "v84", "v85", "v86", "v87",
          "v88", "v89", "v90", "v91", "v92", "v93", "v94", "v95", "v96", "v97",
          "v98", "v99", "v100", "v101", "v102", "v103", "v104", "v105", "v106", "v107",
          "v108", "v109", "v110", "v111", "v112", "v113", "v114", "v115", "v116", "v117",
          "v118", "v119", "v120", "v121", "v122", "v123", "v124", "v125", "v126", "v127",
          "v128", "v129", "v130", "v131", "v132", "v133", "v134", "v135", "v136", "v137",
          "v138", "v139", "v140", "v141", "v142", "v143", "v144", "v145", "v146", "v147",
          "v148", "v149", "v150", "v151", "v152", "v153", "v154", "v155", "v156", "v157",
          "v158", "v159", "v160", "v161", "v162", "v163", "v164", "v165", "v166", "v167",
          "v168", "v169", "v170", "v171", "v172", "v173", "v174", "v175", "v176", "v177",
          "v178", "v179", "v180", "v181", "v182", "v183", "v184", "v185", "v186", "v187",
          "v188", "v189", "v190", "v191");

    if (jq == 0) out[(size_t)b * 256 + dir * HH + q] = h_out;
}

extern "C" void kernel_launch(void* const* d_in, const int* in_sizes, int n_in,
                              void* d_out, int out_size, void* d_ws, size_t ws_size,
                              hipStream_t stream) {
    const float* x = (const float*)d_in[0];
    const int* adj = (const int*)d_in[1];
    const float* wif = (const float*)d_in[2];
    const float* whf = (const float*)d_in[3];
    const float* bif = (const float*)d_in[4];
    const float* bhf = (const float*)d_in[5];
    const float* wib = (const float*)d_in[6];
    const float* whb = (const float*)d_in[7];
    const float* bib = (const float*)d_in[8];
    const float* bhb = (const float*)d_in[9];
    float* out = (float*)d_out;

    // Layout: xpf | xpb | xa. xTh/xTl alias the xpf region: produced by k_xT,
    // consumed by k_agg2, then k_proj overwrites xpf (ordering is safe).
    float* xpf = (float*)d_ws;                 // [N][B][512]
    float* xpb = xpf + (size_t)NN * BB * 512;  // [N][B][512]
    float* xa = xpb + (size_t)NN * BB * 512;   // [B][N][D]
    unsigned short* xth = (unsigned short*)xpf;                 // [B][D][N] bf16
    unsigned short* xtl = xth + (size_t)BB * DD * NN;           // [B][D][N] bf16

    k_xT<<<dim3(NN / 64, DD / 32, BB), 256, 0, stream>>>(x, xth, xtl);
    k_agg2<<<dim3(NN / 64, BB), 256, 0, stream>>>(adj, xth, xtl, xa);
    k_proj<<<dim3((NN * BB) / MT, 1024 / GT), 256, 0, stream>>>(xa, wif, wib, bif, bhf, bib, bhb,
                                                                xpf, xpb);
    k_lstm<<<dim3(BB, 2), 512, 0, stream>>>(xpf, xpb, whf, whb, out);
}

// Round 14
// 1208.877 us; speedup vs baseline: 48.8282x; 1.0313x over previous
//
#include <hip/hip_runtime.h>
#include <math.h>

#define BB 8
#define NN 2048
#define DD 128
#define HH 128

typedef float f4 __attribute__((ext_vector_type(4)));
typedef __attribute__((ext_vector_type(8))) short s16x8;
typedef __attribute__((ext_vector_type(8))) unsigned short u16x8;

__device__ __forceinline__ float fast_rcp(float x) { return __builtin_amdgcn_rcpf(x); }

// round-to-nearest-even bf16 split: x ~= hi + lo (each exactly bf16)
__device__ __forceinline__ void bsplit(float x, unsigned short& h, unsigned short& l) {
    unsigned u = __float_as_uint(x);
    unsigned r = u + 0x7FFFu + ((u >> 16) & 1u);
    h = (unsigned short)(r >> 16);
    float xh = __uint_as_float(((unsigned)h) << 16);
    float d = x - xh;
    unsigned u2 = __float_as_uint(d);
    unsigned r2 = u2 + 0x7FFFu + ((u2 >> 16) & 1u);
    l = (unsigned short)(r2 >> 16);
}

// ---------------- Kernel 0: transpose + bf16-split x ----------------
__global__ __launch_bounds__(256) void k_xT(const float* __restrict__ x,
                                            unsigned short* __restrict__ xth,
                                            unsigned short* __restrict__ xtl) {
    __shared__ __align__(16) unsigned short th[32][72];
    __shared__ __align__(16) unsigned short tl[32][72];
    const int n0 = blockIdx.x * 64;
    const int d0 = blockIdx.y * 32;
    const int b = blockIdx.z;
    const int tid = threadIdx.x;
    {
        const int nl = tid & 63, dseg = tid >> 6;
        const float* xp = x + ((size_t)b * NN + n0 + nl) * DD + d0 + dseg * 8;
        float4 v0 = *(const float4*)(xp);
        float4 v1 = *(const float4*)(xp + 4);
        const float* vv = (const float*)&v0;
#pragma unroll
        for (int j = 0; j < 4; ++j) {
            unsigned short hh, ll;
            bsplit(vv[j], hh, ll);
            th[dseg * 8 + j][nl] = hh;
            tl[dseg * 8 + j][nl] = ll;
        }
        const float* vw = (const float*)&v1;
#pragma unroll
        for (int j = 0; j < 4; ++j) {
            unsigned short hh, ll;
            bsplit(vw[j], hh, ll);
            th[dseg * 8 + 4 + j][nl] = hh;
            tl[dseg * 8 + 4 + j][nl] = ll;
        }
    }
    __syncthreads();
    {
        const int dl = tid >> 3, nseg = tid & 7;
        u16x8 vh = *(const u16x8*)&th[dl][nseg * 8];
        u16x8 vl = *(const u16x8*)&tl[dl][nseg * 8];
        size_t off = ((size_t)b * DD + d0 + dl) * NN + n0 + nseg * 8;
        *(u16x8*)(xth + off) = vh;
        *(u16x8*)(xtl + off) = vl;
    }
}

// ---------------- Kernel 1: graph aggregation via MFMA ----------------
// Emits xa directly as bf16 hi/lo split (row-major [b][n][d]) for k_proj2.
__global__ __launch_bounds__(256) void k_agg2(const int* __restrict__ adj,
                                              const unsigned short* __restrict__ xth,
                                              const unsigned short* __restrict__ xtl,
                                              unsigned short* __restrict__ xah,
                                              unsigned short* __restrict__ xal) {
    __shared__ __align__(16) unsigned short Al[64][40];
    __shared__ __align__(16) unsigned short Xh[128][40];
    __shared__ __align__(16) unsigned short Xl[128][40];
    const int b = blockIdx.y;
    const int i0 = blockIdx.x * 64;
    const int tid = threadIdx.x;
    const int wave = tid >> 6, lane = tid & 63;
    const int ar = tid >> 2, aks = (tid & 3) * 8;
    const int xd = tid >> 1, xks = (tid & 1) * 16;
    const int* ap = adj + ((size_t)b * NN + i0 + ar) * NN + aks;
    const unsigned short* hp = xth + ((size_t)b * DD + xd) * NN + xks;
    const unsigned short* lp = xtl + ((size_t)b * DD + xd) * NN + xks;

    f4 acc[8], dacc;
#pragma unroll
    for (int t = 0; t < 8; ++t) acc[t] = {0.f, 0.f, 0.f, 0.f};
    dacc = {0.f, 0.f, 0.f, 0.f};
    const short onebf = (short)0x3F80;
    s16x8 ones = {onebf, onebf, onebf, onebf, onebf, onebf, onebf, onebf};

    int4 a0 = *(const int4*)(ap);
    int4 a1 = *(const int4*)(ap + 4);
    u16x8 h0 = *(const u16x8*)(hp);
    u16x8 h1 = *(const u16x8*)(hp + 8);
    u16x8 l0 = *(const u16x8*)(lp);
    u16x8 l1 = *(const u16x8*)(lp + 8);

    for (int k0 = 0; k0 < NN; k0 += 32) {
        {
            u16x8 w;
            const int* av0 = (const int*)&a0;
            const int* av1 = (const int*)&a1;
            int colb = k0 + aks, myrow = i0 + ar;
#pragma unroll
            for (int j = 0; j < 4; ++j) {
                int c0 = (av0[j] > 0 ? 1 : 0) + (myrow == colb + j ? 1 : 0);
                int c1 = (av1[j] > 0 ? 1 : 0) + (myrow == colb + 4 + j ? 1 : 0);
                w[j] = c0 == 0 ? 0 : (c0 == 1 ? 0x3F80 : 0x4000);
                w[4 + j] = c1 == 0 ? 0 : (c1 == 1 ? 0x3F80 : 0x4000);
            }
            *(u16x8*)&Al[ar][aks] = w;
            *(u16x8*)&Xh[xd][xks] = h0;
            *(u16x8*)&Xh[xd][xks + 8] = h1;
            *(u16x8*)&Xl[xd][xks] = l0;
            *(u16x8*)&Xl[xd][xks + 8] = l1;
        }
        __syncthreads();
        if (k0 + 32 < NN) {
            a0 = *(const int4*)(ap + k0 + 32);
            a1 = *(const int4*)(ap + k0 + 36);
            h0 = *(const u16x8*)(hp + k0 + 32);
            h1 = *(const u16x8*)(hp + k0 + 40);
            l0 = *(const u16x8*)(lp + k0 + 32);
            l1 = *(const u16x8*)(lp + k0 + 40);
        }
        s16x8 afr = *(const s16x8*)&Al[16 * wave + (lane & 15)][(lane >> 4) * 8];
#pragma unroll
        for (int t = 0; t < 8; ++t) {
            s16x8 bh = *(const s16x8*)&Xh[16 * t + (lane & 15)][(lane >> 4) * 8];
            s16x8 bl = *(const s16x8*)&Xl[16 * t + (lane & 15)][(lane >> 4) * 8];
            acc[t] = __builtin_amdgcn_mfma_f32_16x16x32_bf16(afr, bh, acc[t], 0, 0, 0);
            acc[t] = __builtin_amdgcn_mfma_f32_16x16x32_bf16(afr, bl, acc[t], 0, 0, 0);
        }
        dacc = __builtin_amdgcn_mfma_f32_16x16x32_bf16(afr, ones, dacc, 0, 0, 0);
        __syncthreads();
    }
    float inv[4];
#pragma unroll
    for (int r = 0; r < 4; ++r) inv[r] = fast_rcp(dacc[r]);
#pragma unroll
    for (int t = 0; t < 8; ++t)
#pragma unroll
        for (int r = 0; r < 4; ++r) {
            int row = i0 + 16 * wave + (lane >> 4) * 4 + r;
            float v = acc[t][r] * inv[r];
            unsigned short hh, ll;
            bsplit(v, hh, ll);
            size_t base = ((size_t)b * NN + row) * DD + 16 * t + (lane & 15);
            xah[base] = hh;
            xal[base] = ll;
        }
}

// ---------------- Kernel 2: input projection via MFMA (both dirs) ----------
// xp[(t,b)][gate] = xa[(b,t)][:] . W[gate][:] + bias, split-bf16, permuted
// store p = 4*(g&127)+(g>>7); backward dir time-reversed. Fragment mappings
// identical to k_agg2 (verified): A row=lane&15 k=8*(lane>>4)+j from global;
// B n=lane&15 k-contig from LDS W tile (132-ushort padded rows).
__global__ __launch_bounds__(256) void k_proj2(const unsigned short* __restrict__ xah,
                                               const unsigned short* __restrict__ xal,
                                               const float* __restrict__ wif,
                                               const float* __restrict__ wib,
                                               const float* __restrict__ bif,
                                               const float* __restrict__ bhf,
                                               const float* __restrict__ bib,
                                               const float* __restrict__ bhb,
                                               float* __restrict__ xpf,
                                               float* __restrict__ xpb) {
    __shared__ __align__(16) unsigned short Wh[128][132];
    __shared__ __align__(16) unsigned short Wl[128][132];
    const int rr0 = blockIdx.x * 64;
    const int n0 = blockIdx.y * 128;
    const int tid = threadIdx.x;
    const int wave = tid >> 6, lane = tid & 63;
    {
        int g = tid >> 1;
        int d0 = (tid & 1) * 64;
        int gg = n0 + g;
        const float* wsrc = (gg < 512) ? (wif + (size_t)gg * DD) : (wib + (size_t)(gg - 512) * DD);
#pragma unroll
        for (int j = 0; j < 64; j += 4) {
            float4 v = *(const float4*)(wsrc + d0 + j);
            unsigned short hh, ll;
            bsplit(v.x, hh, ll); Wh[g][d0 + j + 0] = hh; Wl[g][d0 + j + 0] = ll;
            bsplit(v.y, hh, ll); Wh[g][d0 + j + 1] = hh; Wl[g][d0 + j + 1] = ll;
            bsplit(v.z, hh, ll); Wh[g][d0 + j + 2] = hh; Wl[g][d0 + j + 2] = ll;
            bsplit(v.w, hh, ll); Wh[g][d0 + j + 3] = hh; Wl[g][d0 + j + 3] = ll;
        }
    }
    __syncthreads();
    const int arow = rr0 + wave * 16 + (lane & 15);
    const unsigned short* ah = xah + (size_t)arow * DD + ((lane >> 4) * 8);
    const unsigned short* al = xal + (size_t)arow * DD + ((lane >> 4) * 8);
    f4 acc[8];
#pragma unroll
    for (int nt = 0; nt < 8; ++nt) acc[nt] = {0.f, 0.f, 0.f, 0.f};
#pragma unroll
    for (int k0 = 0; k0 < DD; k0 += 32) {
        s16x8 afh = *(const s16x8*)(ah + k0);
        s16x8 afl = *(const s16x8*)(al + k0);
#pragma unroll
        for (int nt = 0; nt < 8; ++nt) {
            s16x8 bh = *(const s16x8*)&Wh[nt * 16 + (lane & 15)][k0 + (lane >> 4) * 8];
            s16x8 bl = *(const s16x8*)&Wl[nt * 16 + (lane & 15)][k0 + (lane >> 4) * 8];
            acc[nt] = __builtin_amdgcn_mfma_f32_16x16x32_bf16(afh, bh, acc[nt], 0, 0, 0);
            acc[nt] = __builtin_amdgcn_mfma_f32_16x16x32_bf16(afl, bh, acc[nt], 0, 0, 0);
            acc[nt] = __builtin_amdgcn_mfma_f32_16x16x32_bf16(afh, bl, acc[nt], 0, 0, 0);
        }
    }
#pragma unroll
    for (int nt = 0; nt < 8; ++nt) {
        int gg = n0 + nt * 16 + (lane & 15);
        float bias = (gg < 512) ? (bif[gg] + bhf[gg]) : (bib[gg - 512] + bhb[gg - 512]);
#pragma unroll
        for (int r = 0; r < 4; ++r) {
            int rr = rr0 + wave * 16 + (lane >> 4) * 4 + r;
            int b = rr >> 11, t = rr & 2047;
            float v = acc[nt][r] + bias;
            if (gg < 512) {
                int pp = 4 * (gg & 127) + (gg >> 7);
                xpf[((size_t)t * BB + b) * 512 + pp] = v;
            } else {
                int gb = gg - 512;
                int pp = 4 * (gb & 127) + (gb >> 7);
                xpb[((size_t)(NN - 1 - t) * BB + b) * 512 + pp] = v;
            }
        }
    }
}

// ---------------- Kernel 3: LSTM recurrence (full inline-asm loop) ---------
// R11/R12 structure (replica-padded LDS, DPP reduce, own-gate activation,
// chunked lgkm waits). R14: 2-step unroll with static even/odd buffers
// (v22/v23 even, v18/v192 odd) + xp ping-pong v19/v20 with vmcnt(1).

#define STRG(x) #x
#define WLD(R0, R3, WOFF, IMM)                                            \
    "global_load_dwordx4 v[" STRG(R0) ":" STRG(R3) "], %[" STRG(WOFF) "], %[whs] offset:" STRG(IMM) "\n\t"
#define PKQ(H0, H1, A0, A1, B0, B1, C0, C1, D0, D1)                                        \
    "v_pk_fma_f32 v[24:25], v[" STRG(A0) ":" STRG(A1) "], v[" STRG(H0) ":" STRG(H1) "], v[24:25]\n\t" \
    "v_pk_fma_f32 v[26:27], v[" STRG(B0) ":" STRG(B1) "], v[" STRG(H0) ":" STRG(H1) "], v[26:27]\n\t" \
    "v_pk_fma_f32 v[28:29], v[" STRG(C0) ":" STRG(C1) "], v[" STRG(H0) ":" STRG(H1) "], v[28:29]\n\t" \
    "v_pk_fma_f32 v[30:31], v[" STRG(D0) ":" STRG(D1) "], v[" STRG(H0) ":" STRG(H1) "], v[30:31]\n\t"
#define PKQ0(H0, H1, A0, A1, B0, B1, C0, C1, D0, D1)                                       \
    "v_pk_mul_f32 v[24:25], v[" STRG(A0) ":" STRG(A1) "], v[" STRG(H0) ":" STRG(H1) "]\n\t" \
    "v_pk_mul_f32 v[26:27], v[" STRG(B0) ":" STRG(B1) "], v[" STRG(H0) ":" STRG(H1) "]\n\t" \
    "v_pk_mul_f32 v[28:29], v[" STRG(C0) ":" STRG(C1) "], v[" STRG(H0) ":" STRG(H1) "]\n\t" \
    "v_pk_mul_f32 v[30:31], v[" STRG(D0) ":" STRG(D1) "], v[" STRG(H0) ":" STRG(H1) "]\n\t"

#define LSTM_BODY(XPD, XPU, RD, WR)                                                        \
    "global_load_dword " XPD ", v21, %[xps]\n\t"                                           \
    "ds_read_b128 v[32:35], " RD "\n\t"                                                    \
    "ds_read_b128 v[36:39], " RD " offset:16\n\t"                                          \
    "ds_read_b128 v[40:43], " RD " offset:32\n\t"                                          \
    "ds_read_b128 v[44:47], " RD " offset:48\n\t"                                          \
    "ds_read_b128 v[48:51], " RD " offset:64\n\t"                                          \
    "ds_read_b128 v[52:55], " RD " offset:80\n\t"                                          \
    "ds_read_b128 v[56:59], " RD " offset:96\n\t"                                          \
    "ds_read_b128 v[60:63], " RD " offset:112\n\t"                                         \
    "v_add_u32 v21, 0x4000, v21\n\t"                                                       \
    "s_waitcnt lgkmcnt(7)\n\t"                                                             \
    PKQ0(32, 33, 64, 65, 96, 97, 128, 129, 160, 161)                                       \
    PKQ(34, 35, 66, 67, 98, 99, 130, 131, 162, 163)                                        \
    "s_waitcnt lgkmcnt(6)\n\t"                                                             \
    PKQ(36, 37, 68, 69, 100, 101, 132, 133, 164, 165)                                      \
    PKQ(38, 39, 70, 71, 102, 103, 134, 135, 166, 167)                                      \
    "s_waitcnt lgkmcnt(5)\n\t"                                                             \
    PKQ(40, 41, 72, 73, 104, 105, 136, 137, 168, 169)                                      \
    PKQ(42, 43, 74, 75, 106, 107, 138, 139, 170, 171)                                      \
    "s_waitcnt lgkmcnt(4)\n\t"                                                             \
    PKQ(44, 45, 76, 77, 108, 109, 140, 141, 172, 173)                                      \
    PKQ(46, 47, 78, 79, 110, 111, 142, 143, 174, 175)                                      \
    "s_waitcnt lgkmcnt(3)\n\t"                                                             \
    PKQ(48, 49, 80, 81, 112, 113, 144, 145, 176, 177)                                      \
    PKQ(50, 51, 82, 83, 114, 115, 146, 147, 178, 179)                                      \
    "s_waitcnt lgkmcnt(2)\n\t"                                                             \
    PKQ(52, 53, 84, 85, 116, 117, 148, 149, 180, 181)                                      \
    PKQ(54, 55, 86, 87, 118, 119, 150, 151, 182, 183)                                      \
    "s_waitcnt lgkmcnt(1)\n\t"                                                             \
    PKQ(56, 57, 88, 89, 120, 121, 152, 153, 184, 185)                                      \
    PKQ(58, 59, 90, 91, 122, 123, 154, 155, 186, 187)                                      \
    "s_waitcnt lgkmcnt(0)\n\t"                                                             \
    PKQ(60, 61, 92, 93, 124, 125, 156, 157, 188, 189)                                      \
    PKQ(62, 63, 94, 95, 126, 127, 158, 159, 190, 191)                                      \
    "v_add_f32 v8, v24, v25\n\t"                                                           \
    "v_add_f32 v9, v26, v27\n\t"                                                           \
    "v_add_f32 v10, v28, v29\n\t"                                                          \
    "v_add_f32 v11, v30, v31\n\t"                                                          \
    "v_mov_b32_dpp v12, v8 quad_perm:[1,0,3,2] row_mask:0xf bank_mask:0xf\n\t"             \
    "v_mov_b32_dpp v13, v9 quad_perm:[1,0,3,2] row_mask:0xf bank_mask:0xf\n\t"             \
    "v_mov_b32_dpp v14, v10 quad_perm:[1,0,3,2] row_mask:0xf bank_mask:0xf\n\t"            \
    "v_mov_b32_dpp v15, v11 quad_perm:[1,0,3,2] row_mask:0xf bank_mask:0xf\n\t"            \
    "v_add_f32 v8, v8, v12\n\t"                                                            \
    "v_add_f32 v9, v9, v13\n\t"                                                            \
    "v_add_f32 v10, v10, v14\n\t"                                                          \
    "v_add_f32 v11, v11, v15\n\t"                                                          \
    "v_mov_b32_dpp v12, v8 quad_perm:[2,3,0,1] row_mask:0xf bank_mask:0xf\n\t"             \
    "v_mov_b32_dpp v13, v9 quad_perm:[2,3,0,1] row_mask:0xf bank_mask:0xf\n\t"             \
    "v_mov_b32_dpp v14, v10 quad_perm:[2,3,0,1] row_mask:0xf bank_mask:0xf\n\t"            \
    "v_mov_b32_dpp v15, v11 quad_perm:[2,3,0,1] row_mask:0xf bank_mask:0xf\n\t"            \
    "v_add_f32 v8, v8, v12\n\t"                                                            \
    "v_add_f32 v9, v9, v13\n\t"                                                            \
    "v_add_f32 v10, v10, v14\n\t"                                                          \
    "v_add_f32 v11, v11, v15\n\t"                                                          \
    "v_mul_f32 v12, %[s0], v8\n\t"                                                         \
    "v_fma_f32 v12, %[s1], v9, v12\n\t"                                                    \
    "v_fma_f32 v12, %[s2], v10, v12\n\t"                                                   \
    "s_waitcnt vmcnt(1)\n\t"                                                               \
    "v_fma_f32 v12, %[s3], v11, v12\n\t"                                                   \
    "v_add_f32 v12, v12, " XPU "\n\t"                                                      \
    "v_mul_f32 v13, %[ml], v12\n\t"                                                        \
    "v_exp_f32 v13, v13\n\t"                                                               \
    "s_nop 1\n\t"                                                                          \
    "v_add_f32 v13, 1.0, v13\n\t"                                                          \
    "v_rcp_f32 v13, v13\n\t"                                                               \
    "s_nop 1\n\t"                                                                          \
    "v_fma_f32 v12, %[Aa], v13, %[Ba]\n\t"                                                 \
    "s_nop 1\n\t"                                                                          \
    "v_mov_b32_dpp v13, v12 quad_perm:[0,0,0,0] row_mask:0xf bank_mask:0xf\n\t"            \
    "v_mov_b32_dpp v14, v12 quad_perm:[2,2,2,2] row_mask:0xf bank_mask:0xf\n\t"            \
    "v_mov_b32_dpp v15, v12 quad_perm:[1,1,1,1] row_mask:0xf bank_mask:0xf\n\t"            \
    "v_mov_b32_dpp v17, v12 quad_perm:[3,3,3,3] row_mask:0xf bank_mask:0xf\n\t"            \
    "v_mul_f32 v13, v13, v14\n\t"                                                          \
    "v_fma_f32 v16, v15, v16, v13\n\t"                                                     \
    "v_mul_f32 v14, 0xc038aa3b, v16\n\t"                                                   \
    "v_exp_f32 v14, v14\n\t"                                                               \
    "s_nop 1\n\t"                                                                          \
    "v_add_f32 v14, 1.0, v14\n\t"                                                          \
    "v_rcp_f32 v14, v14\n\t"                                                               \
    "s_nop 1\n\t"                                                                          \
    "v_fma_f32 v14, 2.0, v14, -1.0\n\t"                                                    \
    "v_mul_f32 v17, v14, v17\n\t"                                                          \
    "ds_write_b32 " WR ", v17\n\t"                                                         \
    "s_waitcnt lgkmcnt(0)\n\t"                                                             \
    "s_barrier\n\t"

__global__ __launch_bounds__(512) void k_lstm(const float* __restrict__ xpf,
                                              const float* __restrict__ xpb,
                                              const float* __restrict__ whf,
                                              const float* __restrict__ whb,
                                              float* __restrict__ out) {
    const int b = blockIdx.x;
    const int dir = blockIdx.y;
    const float* __restrict__ xp = dir ? xpb : xpf;
    const float* __restrict__ wh = dir ? whb : whf;
    const int t = threadIdx.x;  // 0..511
    const int q = t >> 2;       // unit 0..127
    const int jq = t & 3;       // h-col slice / own gate type

    __shared__ __align__(64) float h_lds[1088];
    for (int i = t; i < 1088; i += 512) h_lds[i] = 0.f;
    __syncthreads();

    unsigned hbase = (unsigned)(uintptr_t)&h_lds[0];
    unsigned rd0 = hbase + 672u * (unsigned)jq;                  // buf0 read
    unsigned rd1 = rd0 + 2176u;                                  // buf1 read
    unsigned wrE = hbase + 2176u + 544u * (unsigned)jq + ((unsigned)q << 2);  // even writes buf1
    unsigned wrO = wrE - 2176u;                                  // odd writes buf0
    unsigned w0 = ((0u * 128u + (unsigned)q) * 128u + (unsigned)jq * 32u) * 4u;
    unsigned w1 = ((1u * 128u + (unsigned)q) * 128u + (unsigned)jq * 32u) * 4u;
    unsigned w2 = ((2u * 128u + (unsigned)q) * 128u + (unsigned)jq * 32u) * 4u;
    unsigned w3 = ((3u * 128u + (unsigned)q) * 128u + (unsigned)jq * 32u) * 4u;
    unsigned xoff = (unsigned)(b * 512 + t) * 4u + 16384u;  // prefetch = step 1
    float xp0v = xp[(size_t)b * 512 + t];
    float s0 = (jq == 0) ? 1.f : 0.f;
    float s1 = (jq == 1) ? 1.f : 0.f;
    float s2 = (jq == 2) ? 1.f : 0.f;
    float s3 = (jq == 3) ? 1.f : 0.f;
    float mlv = (jq == 2) ? -2.8853900817779268f : -1.4426950408889634f;
    float Aav = (jq == 2) ? 2.f : 1.f;
    float Bav = (jq == 2) ? -1.f : 0.f;
    float h_out;

    asm volatile(
        "v_mov_b32 v16, 0\n\t"        // c
        "s_movk_i32 s20, 0x400\n\t"   // 1024 double-steps
        "v_mov_b32 v19, %[x0]\n\t"    // xp even
        "v_mov_b32 v21, %[xo]\n\t"    // xp prefetch byte offset
        "v_mov_b32 v22, %[rdb]\n\t"   // read buf0
        "v_mov_b32 v18, %[rdb2]\n\t"  // read buf1
        "v_mov_b32 v23, %[wrb]\n\t"   // write buf1 (even)
        "v_mov_b32 v192, %[wrb2]\n\t" // write buf0 (odd)
        WLD(64, 67, w0, 0) WLD(68, 71, w0, 16) WLD(72, 75, w0, 32) WLD(76, 79, w0, 48)
        WLD(80, 83, w0, 64) WLD(84, 87, w0, 80) WLD(88, 91, w0, 96) WLD(92, 95, w0, 112)
        WLD(96, 99, w1, 0) WLD(100, 103, w1, 16) WLD(104, 107, w1, 32) WLD(108, 111, w1, 48)
        WLD(112, 115, w1, 64) WLD(116, 119, w1, 80) WLD(120, 123, w1, 96) WLD(124, 127, w1, 112)
        WLD(128, 131, w2, 0) WLD(132, 135, w2, 16) WLD(136, 139, w2, 32) WLD(140, 143, w2, 48)
        WLD(144, 147, w2, 64) WLD(148, 151, w2, 80) WLD(152, 155, w2, 96) WLD(156, 159, w2, 112)
        WLD(160, 163, w3, 0) WLD(164, 167, w3, 16) WLD(168, 171, w3, 32) WLD(172, 175, w3, 48)
        WLD(176, 179, w3, 64) WLD(180, 183, w3, 80) WLD(184, 187, w3, 96) WLD(188, 191, w3, 112)
        "s_waitcnt vmcnt(0)\n\t"
        "LSTM_TOP%=:\n\t"
        LSTM_BODY("v20", "v19", "v22", "v23")
        LSTM_BODY("v19", "v20", "v18", "v192")
        "s_sub_u32 s20, s20, 1\n\t"
        "s_cmp_lg_u32 s20, 0\n\t"
        "s_cbranch_scc1 LSTM_TOP%=\n\t"
        "v_mov_b32 %[ho], v17\n\t"
        : [ho] "=v"(h_out)
        : [w0] "v"(w0), [w1] "v"(w1), [w2] "v"(w2), [w3] "v"(w3),
          [whs] "s"(wh), [xps] "s"(xp),
          [xo] "v"(xoff), [rdb] "v"(rd0), [rdb2] "v"(rd1),
          [wrb] "v"(wrE), [wrb2] "v"(wrO), [x0] "v"(xp0v),
          [s0] "v"(s0), [s1] "v"(s1), [s2] "v"(s2), [s3] "v"(s3),
          [ml] "v"(mlv), [Aa] "v"(Aav), [Ba] "v"(Bav)
        : "memory", "vcc", "scc", "s20",
          "v8", "v9", "v10", "v11", "v12", "v13", "v14", "v15", "v16", "v17",
          "v18", "v19", "v20", "v21", "v22", "v23", "v24", "v25", "v26", "v27",
          "v28", "v29", "v30", "v31", "v32", "v33", "v34", "v35", "v36", "v37",
          "v38", "v39", "v40", "v41", "v42", "v43", "v44", "v45", "v46", "v47",
          "v48", "v49", "v50", "v51", "v52", "v53", "v54", "v55", "v56", "v57",
          "v58", "v59", "v60", "v61", "v62", "v63", "v64", "v65", "v66", "v67",
          "v68", "v69", "v70", "v71", "v72", "v73", "v74", "v75", "v76", "v77",
          "v78", "v79", "v80", "v81", "v82", "v83", "v84", "v85", "v86", "v87",
          "v88", "v89", "v90", "v91", "v92", "v93", "v94", "v95", "v96", "v97",
          "v98", "v99", "v100", "v101", "v102", "v103", "v104", "v105", "v106", "v107",
          "v108", "v109", "v110", "v111", "v112", "v113", "v114", "v115", "v116", "v117",
          "v118", "v119", "v120", "v121", "v122", "v123", "v124", "v125", "v126", "v127",
          "v128", "v129", "v130", "v131", "v132", "v133", "v134", "v135", "v136", "v137",
          "v138", "v139", "v140", "v141", "v142", "v143", "v144", "v145", "v146", "v147",
          "v148", "v149", "v150", "v151", "v152", "v153", "v154", "v155", "v156", "v157",
          "v158", "v159", "v160", "v161", "v162", "v163", "v164", "v165", "v166", "v167",
          "v168", "v169", "v170", "v171", "v172", "v173", "v174", "v175", "v176", "v177",
          "v178", "v179", "v180", "v181", "v182", "v183", "v184", "v185", "v186", "v187",
          "v188", "v189", "v190", "v191", "v192");

    if (jq == 0) out[(size_t)b * 256 + dir * HH + q] = h_out;
}

extern "C" void kernel_launch(void* const* d_in, const int* in_sizes, int n_in,
                              void* d_out, int out_size, void* d_ws, size_t ws_size,
                              hipStream_t stream) {
    const float* x = (const float*)d_in[0];
    const int* adj = (const int*)d_in[1];
    const float* wif = (const float*)d_in[2];
    const float* whf = (const float*)d_in[3];
    const float* bif = (const float*)d_in[4];
    const float* bhf = (const float*)d_in[5];
    const float* wib = (const float*)d_in[6];
    const float* whb = (const float*)d_in[7];
    const float* bib = (const float*)d_in[8];
    const float* bhb = (const float*)d_in[9];
    float* out = (float*)d_out;

    // Layout: xpf | xpb | {xah|xal}. xth/xtl alias the xpf region (produced
    // by k_xT, consumed by k_agg2 before k_proj2 writes xpf). The k_lstm
    // last-iteration xp prefetch overrun lands in the following mapped region.
    float* xpf = (float*)d_ws;                          // [N][B][512]
    float* xpb = xpf + (size_t)NN * BB * 512;           // [N][B][512]
    unsigned short* xah = (unsigned short*)(xpb + (size_t)NN * BB * 512);  // [B][N][D]
    unsigned short* xal = xah + (size_t)BB * NN * DD;                      // [B][N][D]
    unsigned short* xth = (unsigned short*)xpf;          // [B][D][N] (temp)
    unsigned short* xtl = xth + (size_t)BB * DD * NN;    // [B][D][N] (temp)

    k_xT<<<dim3(NN / 64, DD / 32, BB), 256, 0, stream>>>(x, xth, xtl);
    k_agg2<<<dim3(NN / 64, BB), 256, 0, stream>>>(adj, xth, xtl, xah, xal);
    k_proj2<<<dim3((NN * BB) / 64, 1024 / 128), 256, 0, stream>>>(xah, xal, wif, wib, bif, bhf,
                                                                  bib, bhb, xpf, xpb);
    k_lstm<<<dim3(BB, 2), 512, 0, stream>>>(xpf, xpb, whf, whb, out);
}

// Round 15
// 1205.060 us; speedup vs baseline: 48.9829x; 1.0032x over previous
//
#include <hip/hip_runtime.h>
#include <math.h>

#define BB 8
#define NN 2048
#define DD 128
#define HH 128

typedef float f4 __attribute__((ext_vector_type(4)));
typedef __attribute__((ext_vector_type(8))) short s16x8;
typedef __attribute__((ext_vector_type(8))) unsigned short u16x8;
typedef __attribute__((ext_vector_type(4))) unsigned short u16x4;

__device__ __forceinline__ float fast_rcp(float x) { return __builtin_amdgcn_rcpf(x); }

// round-to-nearest-even bf16 split: x ~= hi + lo (each exactly bf16)
__device__ __forceinline__ void bsplit(float x, unsigned short& h, unsigned short& l) {
    unsigned u = __float_as_uint(x);
    unsigned r = u + 0x7FFFu + ((u >> 16) & 1u);
    h = (unsigned short)(r >> 16);
    float xh = __uint_as_float(((unsigned)h) << 16);
    float d = x - xh;
    unsigned u2 = __float_as_uint(d);
    unsigned r2 = u2 + 0x7FFFu + ((u2 >> 16) & 1u);
    l = (unsigned short)(r2 >> 16);
}

// ---------------- Kernel 0: transpose + bf16-split x ----------------
__global__ __launch_bounds__(256) void k_xT(const float* __restrict__ x,
                                            unsigned short* __restrict__ xth,
                                            unsigned short* __restrict__ xtl) {
    __shared__ __align__(16) unsigned short th[32][72];
    __shared__ __align__(16) unsigned short tl[32][72];
    const int n0 = blockIdx.x * 64;
    const int d0 = blockIdx.y * 32;
    const int b = blockIdx.z;
    const int tid = threadIdx.x;
    {
        const int nl = tid & 63, dseg = tid >> 6;
        const float* xp = x + ((size_t)b * NN + n0 + nl) * DD + d0 + dseg * 8;
        float4 v0 = *(const float4*)(xp);
        float4 v1 = *(const float4*)(xp + 4);
        const float* vv = (const float*)&v0;
#pragma unroll
        for (int j = 0; j < 4; ++j) {
            unsigned short hh, ll;
            bsplit(vv[j], hh, ll);
            th[dseg * 8 + j][nl] = hh;
            tl[dseg * 8 + j][nl] = ll;
        }
        const float* vw = (const float*)&v1;
#pragma unroll
        for (int j = 0; j < 4; ++j) {
            unsigned short hh, ll;
            bsplit(vw[j], hh, ll);
            th[dseg * 8 + 4 + j][nl] = hh;
            tl[dseg * 8 + 4 + j][nl] = ll;
        }
    }
    __syncthreads();
    {
        const int dl = tid >> 3, nseg = tid & 7;
        u16x8 vh = *(const u16x8*)&th[dl][nseg * 8];
        u16x8 vl = *(const u16x8*)&tl[dl][nseg * 8];
        size_t off = ((size_t)b * DD + d0 + dl) * NN + n0 + nseg * 8;
        *(u16x8*)(xth + off) = vh;
        *(u16x8*)(xtl + off) = vl;
    }
}

// ---------------- Kernel 1: graph aggregation via MFMA ----------------
// R15: 512 threads (2 waves/SIMD -> latency hiding; R14 ran 1 wave/SIMD).
// 8 waves = 4 row-tiles x 2 col-halves of the 64x128 output; fragment
// mappings, LDS geometry (40-ushort rows) and epilogue identical to the
// verified R13/R14 kernel; only the thread->work partition changed.
__global__ __launch_bounds__(512) void k_agg2(const int* __restrict__ adj,
                                              const unsigned short* __restrict__ xth,
                                              const unsigned short* __restrict__ xtl,
                                              unsigned short* __restrict__ xah,
                                              unsigned short* __restrict__ xal) {
    __shared__ __align__(16) unsigned short Al[64][40];
    __shared__ __align__(16) unsigned short Xh[128][40];
    __shared__ __align__(16) unsigned short Xl[128][40];
    const int b = blockIdx.y;
    const int i0 = blockIdx.x * 64;
    const int tid = threadIdx.x;
    const int wave = tid >> 6, lane = tid & 63;
    const int rt = wave >> 1;    // row-tile 0..3 (16 rows each)
    const int colh = wave & 1;   // col-half 0..1 (64 cols each)
    const int ar = tid >> 3, ak = (tid & 7) * 4;   // adj staging: 64 rows x 4 ints
    const int xd = tid >> 2, xks = (tid & 3) * 8;  // xT staging: 128 d x 8 ushorts
    const int* ap = adj + ((size_t)b * NN + i0 + ar) * NN + ak;
    const unsigned short* hp = xth + ((size_t)b * DD + xd) * NN + xks;
    const unsigned short* lp = xtl + ((size_t)b * DD + xd) * NN + xks;

    f4 acc[4], dacc;
#pragma unroll
    for (int t = 0; t < 4; ++t) acc[t] = {0.f, 0.f, 0.f, 0.f};
    dacc = {0.f, 0.f, 0.f, 0.f};
    const short onebf = (short)0x3F80;
    s16x8 ones = {onebf, onebf, onebf, onebf, onebf, onebf, onebf, onebf};

    int4 a0 = *(const int4*)(ap);
    u16x8 h0 = *(const u16x8*)(hp);
    u16x8 l0 = *(const u16x8*)(lp);

    for (int k0 = 0; k0 < NN; k0 += 32) {
        {
            u16x4 w;
            const int* av = (const int*)&a0;
            int colb = k0 + ak, myrow = i0 + ar;
#pragma unroll
            for (int j = 0; j < 4; ++j) {
                int c = (av[j] > 0 ? 1 : 0) + (myrow == colb + j ? 1 : 0);
                w[j] = c == 0 ? 0 : (c == 1 ? 0x3F80 : 0x4000);
            }
            *(u16x4*)&Al[ar][ak] = w;
            *(u16x8*)&Xh[xd][xks] = h0;
            *(u16x8*)&Xl[xd][xks] = l0;
        }
        __syncthreads();
        if (k0 + 32 < NN) {  // prefetch next tile into regs (overlaps compute)
            a0 = *(const int4*)(ap + k0 + 32);
            h0 = *(const u16x8*)(hp + k0 + 32);
            l0 = *(const u16x8*)(lp + k0 + 32);
        }
        s16x8 afr = *(const s16x8*)&Al[rt * 16 + (lane & 15)][(lane >> 4) * 8];
#pragma unroll
        for (int t = 0; t < 4; ++t) {
            s16x8 bh = *(const s16x8*)&Xh[colh * 64 + 16 * t + (lane & 15)][(lane >> 4) * 8];
            s16x8 bl = *(const s16x8*)&Xl[colh * 64 + 16 * t + (lane & 15)][(lane >> 4) * 8];
            acc[t] = __builtin_amdgcn_mfma_f32_16x16x32_bf16(afr, bh, acc[t], 0, 0, 0);
            acc[t] = __builtin_amdgcn_mfma_f32_16x16x32_bf16(afr, bl, acc[t], 0, 0, 0);
        }
        dacc = __builtin_amdgcn_mfma_f32_16x16x32_bf16(afr, ones, dacc, 0, 0, 0);
        __syncthreads();
    }
    float inv[4];
#pragma unroll
    for (int r = 0; r < 4; ++r) inv[r] = fast_rcp(dacc[r]);
#pragma unroll
    for (int t = 0; t < 4; ++t)
#pragma unroll
        for (int r = 0; r < 4; ++r) {
            int row = i0 + rt * 16 + (lane >> 4) * 4 + r;
            int col = colh * 64 + 16 * t + (lane & 15);
            float v = acc[t][r] * inv[r];
            unsigned short hh, ll;
            bsplit(v, hh, ll);
            size_t base = ((size_t)b * NN + row) * DD + col;
            xah[base] = hh;
            xal[base] = ll;
        }
}

// ---------------- Kernel 2: input projection via MFMA (both dirs) ----------
__global__ __launch_bounds__(256) void k_proj2(const unsigned short* __restrict__ xah,
                                               const unsigned short* __restrict__ xal,
                                               const float* __restrict__ wif,
                                               const float* __restrict__ wib,
                                               const float* __restrict__ bif,
                                               const float* __restrict__ bhf,
                                               const float* __restrict__ bib,
                                               const float* __restrict__ bhb,
                                               float* __restrict__ xpf,
                                               float* __restrict__ xpb) {
    __shared__ __align__(16) unsigned short Wh[128][132];
    __shared__ __align__(16) unsigned short Wl[128][132];
    const int rr0 = blockIdx.x * 64;
    const int n0 = blockIdx.y * 128;
    const int tid = threadIdx.x;
    const int wave = tid >> 6, lane = tid & 63;
    {
        int g = tid >> 1;
        int d0 = (tid & 1) * 64;
        int gg = n0 + g;
        const float* wsrc = (gg < 512) ? (wif + (size_t)gg * DD) : (wib + (size_t)(gg - 512) * DD);
#pragma unroll
        for (int j = 0; j < 64; j += 4) {
            float4 v = *(const float4*)(wsrc + d0 + j);
            unsigned short hh, ll;
            bsplit(v.x, hh, ll); Wh[g][d0 + j + 0] = hh; Wl[g][d0 + j + 0] = ll;
            bsplit(v.y, hh, ll); Wh[g][d0 + j + 1] = hh; Wl[g][d0 + j + 1] = ll;
            bsplit(v.z, hh, ll); Wh[g][d0 + j + 2] = hh; Wl[g][d0 + j + 2] = ll;
            bsplit(v.w, hh, ll); Wh[g][d0 + j + 3] = hh; Wl[g][d0 + j + 3] = ll;
        }
    }
    __syncthreads();
    const int arow = rr0 + wave * 16 + (lane & 15);
    const unsigned short* ah = xah + (size_t)arow * DD + ((lane >> 4) * 8);
    const unsigned short* al = xal + (size_t)arow * DD + ((lane >> 4) * 8);
    f4 acc[8];
#pragma unroll
    for (int nt = 0; nt < 8; ++nt) acc[nt] = {0.f, 0.f, 0.f, 0.f};
#pragma unroll
    for (int k0 = 0; k0 < DD; k0 += 32) {
        s16x8 afh = *(const s16x8*)(ah + k0);
        s16x8 afl = *(const s16x8*)(al + k0);
#pragma unroll
        for (int nt = 0; nt < 8; ++nt) {
            s16x8 bh = *(const s16x8*)&Wh[nt * 16 + (lane & 15)][k0 + (lane >> 4) * 8];
            s16x8 bl = *(const s16x8*)&Wl[nt * 16 + (lane & 15)][k0 + (lane >> 4) * 8];
            acc[nt] = __builtin_amdgcn_mfma_f32_16x16x32_bf16(afh, bh, acc[nt], 0, 0, 0);
            acc[nt] = __builtin_amdgcn_mfma_f32_16x16x32_bf16(afl, bh, acc[nt], 0, 0, 0);
            acc[nt] = __builtin_amdgcn_mfma_f32_16x16x32_bf16(afh, bl, acc[nt], 0, 0, 0);
        }
    }
#pragma unroll
    for (int nt = 0; nt < 8; ++nt) {
        int gg = n0 + nt * 16 + (lane & 15);
        float bias = (gg < 512) ? (bif[gg] + bhf[gg]) : (bib[gg - 512] + bhb[gg - 512]);
#pragma unroll
        for (int r = 0; r < 4; ++r) {
            int rr = rr0 + wave * 16 + (lane >> 4) * 4 + r;
            int b = rr >> 11, t = rr & 2047;
            float v = acc[nt][r] + bias;
            if (gg < 512) {
                int pp = 4 * (gg & 127) + (gg >> 7);
                xpf[((size_t)t * BB + b) * 512 + pp] = v;
            } else {
                int gb = gg - 512;
                int pp = 4 * (gb & 127) + (gb >> 7);
                xpb[((size_t)(NN - 1 - t) * BB + b) * 512 + pp] = v;
            }
        }
    }
}

// ---------------- Kernel 3: LSTM recurrence (full inline-asm loop) ---------
// R11/R12 structure (replica-padded LDS, DPP reduce, own-gate activation,
// chunked lgkm waits) + R14 2-step unroll. Unchanged from R14 (verified).

#define STRG(x) #x
#define WLD(R0, R3, WOFF, IMM)                                            \
    "global_load_dwordx4 v[" STRG(R0) ":" STRG(R3) "], %[" STRG(WOFF) "], %[whs] offset:" STRG(IMM) "\n\t"
#define PKQ(H0, H1, A0, A1, B0, B1, C0, C1, D0, D1)                                        \
    "v_pk_fma_f32 v[24:25], v[" STRG(A0) ":" STRG(A1) "], v[" STRG(H0) ":" STRG(H1) "], v[24:25]\n\t" \
    "v_pk_fma_f32 v[26:27], v[" STRG(B0) ":" STRG(B1) "], v[" STRG(H0) ":" STRG(H1) "], v[26:27]\n\t" \
    "v_pk_fma_f32 v[28:29], v[" STRG(C0) ":" STRG(C1) "], v[" STRG(H0) ":" STRG(H1) "], v[28:29]\n\t" \
    "v_pk_fma_f32 v[30:31], v[" STRG(D0) ":" STRG(D1) "], v[" STRG(H0) ":" STRG(H1) "], v[30:31]\n\t"
#define PKQ0(H0, H1, A0, A1, B0, B1, C0, C1, D0, D1)                                       \
    "v_pk_mul_f32 v[24:25], v[" STRG(A0) ":" STRG(A1) "], v[" STRG(H0) ":" STRG(H1) "]\n\t" \
    "v_pk_mul_f32 v[26:27], v[" STRG(B0) ":" STRG(B1) "], v[" STRG(H0) ":" STRG(H1) "]\n\t" \
    "v_pk_mul_f32 v[28:29], v[" STRG(C0) ":" STRG(C1) "], v[" STRG(H0) ":" STRG(H1) "]\n\t" \
    "v_pk_mul_f32 v[30:31], v[" STRG(D0) ":" STRG(D1) "], v[" STRG(H0) ":" STRG(H1) "]\n\t"

#define LSTM_BODY(XPD, XPU, RD, WR)                                                        \
    "global_load_dword " XPD ", v21, %[xps]\n\t"                                           \
    "ds_read_b128 v[32:35], " RD "\n\t"                                                    \
    "ds_read_b128 v[36:39], " RD " offset:16\n\t"                                          \
    "ds_read_b128 v[40:43], " RD " offset:32\n\t"                                          \
    "ds_read_b128 v[44:47], " RD " offset:48\n\t"                                          \
    "ds_read_b128 v[48:51], " RD " offset:64\n\t"                                          \
    "ds_read_b128 v[52:55], " RD " offset:80\n\t"                                          \
    "ds_read_b128 v[56:59], " RD " offset:96\n\t"                                          \
    "ds_read_b128 v[60:63], " RD " offset:112\n\t"                                         \
    "v_add_u32 v21, 0x4000, v21\n\t"                                                       \
    "s_waitcnt lgkmcnt(7)\n\t"                                                             \
    PKQ0(32, 33, 64, 65, 96, 97, 128, 129, 160, 161)                                       \
    PKQ(34, 35, 66, 67, 98, 99, 130, 131, 162, 163)                                        \
    "s_waitcnt lgkmcnt(6)\n\t"                                                             \
    PKQ(36, 37, 68, 69, 100, 101, 132, 133, 164, 165)                                      \
    PKQ(38, 39, 70, 71, 102, 103, 134, 135, 166, 167)                                      \
    "s_waitcnt lgkmcnt(5)\n\t"                                                             \
    PKQ(40, 41, 72, 73, 104, 105, 136, 137, 168, 169)                                      \
    PKQ(42, 43, 74, 75, 106, 107, 138, 139, 170, 171)                                      \
    "s_waitcnt lgkmcnt(4)\n\t"                                                             \
    PKQ(44, 45, 76, 77, 108, 109, 140, 141, 172, 173)                                      \
    PKQ(46, 47, 78, 79, 110, 111, 142, 143, 174, 175)                                      \
    "s_waitcnt lgkmcnt(3)\n\t"                                                             \
    PKQ(48, 49, 80, 81, 112, 113, 144, 145, 176, 177)                                      \
    PKQ(50, 51, 82, 83, 114, 115, 146, 147, 178, 179)                                      \
    "s_waitcnt lgkmcnt(2)\n\t"                                                             \
    PKQ(52, 53, 84, 85, 116, 117, 148, 149, 180, 181)                                      \
    PKQ(54, 55, 86, 87, 118, 119, 150, 151, 182, 183)                                      \
    "s_waitcnt lgkmcnt(1)\n\t"                                                             \
    PKQ(56, 57, 88, 89, 120, 121, 152, 153, 184, 185)                                      \
    PKQ(58, 59, 90, 91, 122, 123, 154, 155, 186, 187)                                      \
    "s_waitcnt lgkmcnt(0)\n\t"                                                             \
    PKQ(60, 61, 92, 93, 124, 125, 156, 157, 188, 189)                                      \
    PKQ(62, 63, 94, 95, 126, 127, 158, 159, 190, 191)                                      \
    "v_add_f32 v8, v24, v25\n\t"                                                           \
    "v_add_f32 v9, v26, v27\n\t"                                                           \
    "v_add_f32 v10, v28, v29\n\t"                                                          \
    "v_add_f32 v11, v30, v31\n\t"                                                          \
    "v_mov_b32_dpp v12, v8 quad_perm:[1,0,3,2] row_mask:0xf bank_mask:0xf\n\t"             \
    "v_mov_b32_dpp v13, v9 quad_perm:[1,0,3,2] row_mask:0xf bank_mask:0xf\n\t"             \
    "v_mov_b32_dpp v14, v10 quad_perm:[1,0,3,2] row_mask:0xf bank_mask:0xf\n\t"            \
    "v_mov_b32_dpp v15, v11 quad_perm:[1,0,3,2] row_mask:0xf bank_mask:0xf\n\t"            \
    "v_add_f32 v8, v8, v12\n\t"                                                            \
    "v_add_f32 v9, v9, v13\n\t"                                                            \
    "v_add_f32 v10, v10, v14\n\t"                                                          \
    "v_add_f32 v11, v11, v15\n\t"                                                          \
    "v_mov_b32_dpp v12, v8 quad_perm:[2,3,0,1] row_mask:0xf bank_mask:0xf\n\t"             \
    "v_mov_b32_dpp v13, v9 quad_perm:[2,3,0,1] row_mask:0xf bank_mask:0xf\n\t"             \
    "v_mov_b32_dpp v14, v10 quad_perm:[2,3,0,1] row_mask:0xf bank_mask:0xf\n\t"            \
    "v_mov_b32_dpp v15, v11 quad_perm:[2,3,0,1] row_mask:0xf bank_mask:0xf\n\t"            \
    "v_add_f32 v8, v8, v12\n\t"                                                            \
    "v_add_f32 v9, v9, v13\n\t"                                                            \
    "v_add_f32 v10, v10, v14\n\t"                                                          \
    "v_add_f32 v11, v11, v15\n\t"                                                          \
    "v_mul_f32 v12, %[s0], v8\n\t"                                                         \
    "v_fma_f32 v12, %[s1], v9, v12\n\t"                                                    \
    "v_fma_f32 v12, %[s2], v10, v12\n\t"                                                   \
    "s_waitcnt vmcnt(1)\n\t"                                                               \
    "v_fma_f32 v12, %[s3], v11, v12\n\t"                                                   \
    "v_add_f32 v12, v12, " XPU "\n\t"                                                      \
    "v_mul_f32 v13, %[ml], v12\n\t"                                                        \
    "v_exp_f32 v13, v13\n\t"                                                               \
    "s_nop 1\n\t"                                                                          \
    "v_add_f32 v13, 1.0, v13\n\t"                                                          \
    "v_rcp_f32 v13, v13\n\t"                                                               \
    "s_nop 1\n\t"                                                                          \
    "v_fma_f32 v12, %[Aa], v13, %[Ba]\n\t"                                                 \
    "s_nop 1\n\t"                                                                          \
    "v_mov_b32_dpp v13, v12 quad_perm:[0,0,0,0] row_mask:0xf bank_mask:0xf\n\t"            \
    "v_mov_b32_dpp v14, v12 quad_perm:[2,2,2,2] row_mask:0xf bank_mask:0xf\n\t"            \
    "v_mov_b32_dpp v15, v12 quad_perm:[1,1,1,1] row_mask:0xf bank_mask:0xf\n\t"            \
    "v_mov_b32_dpp v17, v12 quad_perm:[3,3,3,3] row_mask:0xf bank_mask:0xf\n\t"            \
    "v_mul_f32 v13, v13, v14\n\t"                                                          \
    "v_fma_f32 v16, v15, v16, v13\n\t"                                                     \
    "v_mul_f32 v14, 0xc038aa3b, v16\n\t"                                                   \
    "v_exp_f32 v14, v14\n\t"                                                               \
    "s_nop 1\n\t"                                                                          \
    "v_add_f32 v14, 1.0, v14\n\t"                                                          \
    "v_rcp_f32 v14, v14\n\t"                                                               \
    "s_nop 1\n\t"                                                                          \
    "v_fma_f32 v14, 2.0, v14, -1.0\n\t"                                                    \
    "v_mul_f32 v17, v14, v17\n\t"                                                          \
    "ds_write_b32 " WR ", v17\n\t"                                                         \
    "s_waitcnt lgkmcnt(0)\n\t"                                                             \
    "s_barrier\n\t"

__global__ __launch_bounds__(512) void k_lstm(const float* __restrict__ xpf,
                                              const float* __restrict__ xpb,
                                              const float* __restrict__ whf,
                                              const float* __restrict__ whb,
                                              float* __restrict__ out) {
    const int b = blockIdx.x;
    const int dir = blockIdx.y;
    const float* __restrict__ xp = dir ? xpb : xpf;
    const float* __restrict__ wh = dir ? whb : whf;
    const int t = threadIdx.x;  // 0..511
    const int q = t >> 2;       // unit 0..127
    const int jq = t & 3;       // h-col slice / own gate type

    __shared__ __align__(64) float h_lds[1088];
    for (int i = t; i < 1088; i += 512) h_lds[i] = 0.f;
    __syncthreads();

    unsigned hbase = (unsigned)(uintptr_t)&h_lds[0];
    unsigned rd0 = hbase + 672u * (unsigned)jq;                  // buf0 read
    unsigned rd1 = rd0 + 2176u;                                  // buf1 read
    unsigned wrE = hbase + 2176u + 544u * (unsigned)jq + ((unsigned)q << 2);  // even writes buf1
    unsigned wrO = wrE - 2176u;                                  // odd writes buf0
    unsigned w0 = ((0u * 128u + (unsigned)q) * 128u + (unsigned)jq * 32u) * 4u;
    unsigned w1 = ((1u * 128u + (unsigned)q) * 128u + (unsigned)jq * 32u) * 4u;
    unsigned w2 = ((2u * 128u + (unsigned)q) * 128u + (unsigned)jq * 32u) * 4u;
    unsigned w3 = ((3u * 128u + (unsigned)q) * 128u + (unsigned)jq * 32u) * 4u;
    unsigned xoff = (unsigned)(b * 512 + t) * 4u + 16384u;  // prefetch = step 1
    float xp0v = xp[(size_t)b * 512 + t];
    float s0 = (jq == 0) ? 1.f : 0.f;
    float s1 = (jq == 1) ? 1.f : 0.f;
    float s2 = (jq == 2) ? 1.f : 0.f;
    float s3 = (jq == 3) ? 1.f : 0.f;
    float mlv = (jq == 2) ? -2.8853900817779268f : -1.4426950408889634f;
    float Aav = (jq == 2) ? 2.f : 1.f;
    float Bav = (jq == 2) ? -1.f : 0.f;
    float h_out;

    asm volatile(
        "v_mov_b32 v16, 0\n\t"        // c
        "s_movk_i32 s20, 0x400\n\t"   // 1024 double-steps
        "v_mov_b32 v19, %[x0]\n\t"    // xp even
        "v_mov_b32 v21, %[xo]\n\t"    // xp prefetch byte offset
        "v_mov_b32 v22, %[rdb]\n\t"   // read buf0
        "v_mov_b32 v18, %[rdb2]\n\t"  // read buf1
        "v_mov_b32 v23, %[wrb]\n\t"   // write buf1 (even)
        "v_mov_b32 v192, %[wrb2]\n\t" // write buf0 (odd)
        WLD(64, 67, w0, 0) WLD(68, 71, w0, 16) WLD(72, 75, w0, 32) WLD(76, 79, w0, 48)
        WLD(80, 83, w0, 64) WLD(84, 87, w0, 80) WLD(88, 91, w0, 96) WLD(92, 95, w0, 112)
        WLD(96, 99, w1, 0) WLD(100, 103, w1, 16) WLD(104, 107, w1, 32) WLD(108, 111, w1, 48)
        WLD(112, 115, w1, 64) WLD(116, 119, w1, 80) WLD(120, 123, w1, 96) WLD(124, 127, w1, 112)
        WLD(128, 131, w2, 0) WLD(132, 135, w2, 16) WLD(136, 139, w2, 32) WLD(140, 143, w2, 48)
        WLD(144, 147, w2, 64) WLD(148, 151, w2, 80) WLD(152, 155, w2, 96) WLD(156, 159, w2, 112)
        WLD(160, 163, w3, 0) WLD(164, 167, w3, 16) WLD(168, 171, w3, 32) WLD(172, 175, w3, 48)
        WLD(176, 179, w3, 64) WLD(180, 183, w3, 80) WLD(184, 187, w3, 96) WLD(188, 191, w3, 112)
        "s_waitcnt vmcnt(0)\n\t"
        "LSTM_TOP%=:\n\t"
        LSTM_BODY("v20", "v19", "v22", "v23")
        LSTM_BODY("v19", "v20", "v18", "v192")
        "s_sub_u32 s20, s20, 1\n\t"
        "s_cmp_lg_u32 s20, 0\n\t"
        "s_cbranch_scc1 LSTM_TOP%=\n\t"
        "v_mov_b32 %[ho], v17\n\t"
        : [ho] "=v"(h_out)
        : [w0] "v"(w0), [w1] "v"(w1), [w2] "v"(w2), [w3] "v"(w3),
          [whs] "s"(wh), [xps] "s"(xp),
          [xo] "v"(xoff), [rdb] "v"(rd0), [rdb2] "v"(rd1),
          [wrb] "v"(wrE), [wrb2] "v"(wrO), [x0] "v"(xp0v),
          [s0] "v"(s0), [s1] "v"(s1), [s2] "v"(s2), [s3] "v"(s3),
          [ml] "v"(mlv), [Aa] "v"(Aav), [Ba] "v"(Bav)
        : "memory", "vcc", "scc", "s20",
          "v8", "v9", "v10", "v11", "v12", "v13", "v14", "v15", "v16", "v17",
          "v18", "v19", "v20", "v21", "v22", "v23", "v24", "v25", "v26", "v27",
          "v28", "v29", "v30", "v31", "v32", "v33", "v34", "v35", "v36", "v37",
          "v38", "v39", "v40", "v41", "v42", "v43", "v44", "v45", "v46", "v47",
          "v48", "v49", "v50", "v51", "v52", "v53", "v54", "v55", "v56", "v57",
          "v58", "v59", "v60", "v61", "v62", "v63", "v64", "v65", "v66", "v67",
          "v68", "v69", "v70", "v71", "v72", "v73", "v74", "v75", "v76", "v77",
          "v78", "v79", "v80", "v81", "v82", "v83", "v84", "v85", "v86", "v87",
          "v88", "v89", "v90", "v91", "v92", "v93", "v94", "v95", "v96", "v97",
          "v98", "v99", "v100", "v101", "v102", "v103", "v104", "v105", "v106", "v107",
          "v108", "v109", "v110", "v111", "v112", "v113", "v114", "v115", "v116", "v117",
          "v118", "v119", "v120", "v121", "v122", "v123", "v124", "v125", "v126", "v127",
          "v128", "v129", "v130", "v131", "v132", "v133", "v134", "v135", "v136", "v137",
          "v138", "v139", "v140", "v141", "v142", "v143", "v144", "v145", "v146", "v147",
          "v148", "v149", "v150", "v151", "v152", "v153", "v154", "v155", "v156", "v157",
          "v158", "v159", "v160", "v161", "v162", "v163", "v164", "v165", "v166", "v167",
          "v168", "v169", "v170", "v171", "v172", "v173", "v174", "v175", "v176", "v177",
          "v178", "v179", "v180", "v181", "v182", "v183", "v184", "v185", "v186", "v187",
          "v188", "v189", "v190", "v191", "v192");

    if (jq == 0) out[(size_t)b * 256 + dir * HH + q] = h_out;
}

extern "C" void kernel_launch(void* const* d_in, const int* in_sizes, int n_in,
                              void* d_out, int out_size, void* d_ws, size_t ws_size,
                              hipStream_t stream) {
    const float* x = (const float*)d_in[0];
    const int* adj = (const int*)d_in[1];
    const float* wif = (const float*)d_in[2];
    const float* whf = (const float*)d_in[3];
    const float* bif = (const float*)d_in[4];
    const float* bhf = (const float*)d_in[5];
    const float* wib = (const float*)d_in[6];
    const float* whb = (const float*)d_in[7];
    const float* bib = (const float*)d_in[8];
    const float* bhb = (const float*)d_in[9];
    float* out = (float*)d_out;

    // Layout: xpf | xpb | {xah|xal}. xth/xtl alias the xpf region (produced
    // by k_xT, consumed by k_agg2 before k_proj2 writes xpf). The k_lstm
    // last-iteration xp prefetch overrun lands in the following mapped region.
    float* xpf = (float*)d_ws;                          // [N][B][512]
    float* xpb = xpf + (size_t)NN * BB * 512;           // [N][B][512]
    unsigned short* xah = (unsigned short*)(xpb + (size_t)NN * BB * 512);  // [B][N][D]
    unsigned short* xal = xah + (size_t)BB * NN * DD;                      // [B][N][D]
    unsigned short* xth = (unsigned short*)xpf;          // [B][D][N] (temp)
    unsigned short* xtl = xth + (size_t)BB * DD * NN;    // [B][D][N] (temp)

    k_xT<<<dim3(NN / 64, DD / 32, BB), 256, 0, stream>>>(x, xth, xtl);
    k_agg2<<<dim3(NN / 64, BB), 512, 0, stream>>>(adj, xth, xtl, xah, xal);
    k_proj2<<<dim3((NN * BB) / 64, 1024 / 128), 256, 0, stream>>>(xah, xal, wif, wib, bif, bhf,
                                                                  bib, bhb, xpf, xpb);
    k_lstm<<<dim3(BB, 2), 512, 0, stream>>>(xpf, xpb, whf, whb, out);
}